// Round 1
// baseline (1425.868 us; speedup 1.0000x reference)
//
#include <hip/hip_runtime.h>
#include <math.h>

// ---------------- problem constants ----------------
#define DIM_   1024
#define STATE_ 64
#define HEADS_ 8
#define INNER_ 2048
#define HDIM_  256          // INNER/HEADS
#define B_     2
#define L_     2048
#define M_     (B_*L_)      // 4096 rows total
#define HS_    (HEADS_*STATE_)   // 512
#define EPS_   1e-5f
#define Q_     64           // SSD chunk length
#define NC_    (L_/Q_)      // 32 chunks per sequence
#define NCHUNK_ (B_*HEADS_*NC_)  // 512 chunk-blocks

static_assert(M_ % 128 == 0 && INNER_ % 128 == 0 && DIM_ % 128 == 0 && HS_ % 128 == 0, "tiles");

__device__ __forceinline__ float siluf(float x) { return x / (1.f + expf(-x)); }

// ---------------- generic SGEMM: C[M x N] = A[M x K] * W[N x K]^T ----------------
// 128x128 tile, BK=16, 256 threads, 8x8 per thread, register-prefetch double buffer.
__global__ __launch_bounds__(256) void sgemm_nt(const float* __restrict__ A,
                                                const float* __restrict__ W,
                                                float* __restrict__ C,
                                                int Kdim, int Ndim) {
    __shared__ float As[16][132];
    __shared__ float Ws[16][132];
    const int tid = threadIdx.x;
    const int bm = blockIdx.y * 128;
    const int bn = blockIdx.x * 128;
    const int tx = tid & 15;
    const int ty = tid >> 4;

    float acc[8][8];
#pragma unroll
    for (int i = 0; i < 8; ++i)
#pragma unroll
        for (int j = 0; j < 8; ++j) acc[i][j] = 0.f;

    const int r0 = tid >> 2;          // 0..63
    const int kc = (tid & 3) * 4;     // 0,4,8,12
    const float* Ap0 = A + (size_t)(bm + r0) * Kdim + kc;
    const float* Ap1 = A + (size_t)(bm + r0 + 64) * Kdim + kc;
    const float* Wp0 = W + (size_t)(bn + r0) * Kdim + kc;
    const float* Wp1 = W + (size_t)(bn + r0 + 64) * Kdim + kc;

    float4 pa0 = *(const float4*)Ap0;
    float4 pa1 = *(const float4*)Ap1;
    float4 pw0 = *(const float4*)Wp0;
    float4 pw1 = *(const float4*)Wp1;

    for (int k0 = 0; k0 < Kdim; k0 += 16) {
        __syncthreads();
        As[kc+0][r0] = pa0.x; As[kc+1][r0] = pa0.y; As[kc+2][r0] = pa0.z; As[kc+3][r0] = pa0.w;
        As[kc+0][r0+64] = pa1.x; As[kc+1][r0+64] = pa1.y; As[kc+2][r0+64] = pa1.z; As[kc+3][r0+64] = pa1.w;
        Ws[kc+0][r0] = pw0.x; Ws[kc+1][r0] = pw0.y; Ws[kc+2][r0] = pw0.z; Ws[kc+3][r0] = pw0.w;
        Ws[kc+0][r0+64] = pw1.x; Ws[kc+1][r0+64] = pw1.y; Ws[kc+2][r0+64] = pw1.z; Ws[kc+3][r0+64] = pw1.w;
        __syncthreads();
        if (k0 + 16 < Kdim) {
            pa0 = *(const float4*)(Ap0 + k0 + 16);
            pa1 = *(const float4*)(Ap1 + k0 + 16);
            pw0 = *(const float4*)(Wp0 + k0 + 16);
            pw1 = *(const float4*)(Wp1 + k0 + 16);
        }
#pragma unroll
        for (int kk = 0; kk < 16; ++kk) {
            float a[8], w[8];
            *(float4*)&a[0] = *(const float4*)&As[kk][ty*4];
            *(float4*)&a[4] = *(const float4*)&As[kk][ty*4+64];
            *(float4*)&w[0] = *(const float4*)&Ws[kk][tx*4];
            *(float4*)&w[4] = *(const float4*)&Ws[kk][tx*4+64];
#pragma unroll
            for (int i = 0; i < 8; ++i)
#pragma unroll
                for (int j = 0; j < 8; ++j)
                    acc[i][j] += a[i] * w[j];
        }
    }
#pragma unroll
    for (int i = 0; i < 8; ++i) {
        int m = bm + ty*4 + (i & 3) + ((i >> 2) * 64);
        float4 v0 = make_float4(acc[i][0], acc[i][1], acc[i][2], acc[i][3]);
        float4 v1 = make_float4(acc[i][4], acc[i][5], acc[i][6], acc[i][7]);
        *(float4*)&C[(size_t)m * Ndim + bn + tx*4]      = v0;
        *(float4*)&C[(size_t)m * Ndim + bn + 64 + tx*4] = v1;
    }
}

// ---------------- causal depthwise conv (K=4) + bias + SiLU ----------------
__global__ __launch_bounds__(256) void conv_silu_k(const float* __restrict__ xpre,
                                                   const float* __restrict__ cw,
                                                   const float* __restrict__ cb,
                                                   float* __restrict__ xc) {
    int idx = blockIdx.x * 256 + threadIdx.x;      // over M_*INNER_/4
    int c = (idx & (INNER_/4 - 1)) * 4;
    int m = idx >> 9;                               // / (INNER_/4)
    int t = m & (L_ - 1);
    float4 acc = make_float4(cb[c], cb[c+1], cb[c+2], cb[c+3]);
#pragma unroll
    for (int k = 0; k < 4; ++k) {
        int tt = t - 3 + k;
        if (tt >= 0) {
            float4 xv = *(const float4*)&xpre[(size_t)(m - 3 + k) * INNER_ + c];
            acc.x += xv.x * cw[(c+0)*4 + k];
            acc.y += xv.y * cw[(c+1)*4 + k];
            acc.z += xv.z * cw[(c+2)*4 + k];
            acc.w += xv.w * cw[(c+3)*4 + k];
        }
    }
    acc.x = siluf(acc.x); acc.y = siluf(acc.y); acc.z = siluf(acc.z); acc.w = siluf(acc.w);
    *(float4*)&xc[(size_t)m * INNER_ + c] = acc;
}

// ---------------- dt = softplus(x @ Wdt^T + b_dt), one wave per row ----------------
__global__ __launch_bounds__(256) void dt_proj_k(const float* __restrict__ xc,
                                                 const float* __restrict__ Wdt,
                                                 const float* __restrict__ bdt,
                                                 float* __restrict__ dtb) {
    int row = (blockIdx.x * 256 + threadIdx.x) >> 6;
    int lane = threadIdx.x & 63;
    const float* xr = xc + (size_t)row * INNER_;
    float p[HEADS_];
#pragma unroll
    for (int h = 0; h < HEADS_; ++h) p[h] = 0.f;
    for (int k = lane * 4; k < INNER_; k += 256) {
        float4 xv = *(const float4*)&xr[k];
#pragma unroll
        for (int h = 0; h < HEADS_; ++h) {
            float4 wv = *(const float4*)&Wdt[h*INNER_ + k];
            p[h] += xv.x*wv.x + xv.y*wv.y + xv.z*wv.z + xv.w*wv.w;
        }
    }
#pragma unroll
    for (int h = 0; h < HEADS_; ++h)
#pragma unroll
        for (int off = 32; off > 0; off >>= 1)
            p[h] += __shfl_down(p[h], off, 64);
    if (lane == 0) {
#pragma unroll
        for (int h = 0; h < HEADS_; ++h) {
            float v = p[h] + bdt[h];
            dtb[(size_t)row * HEADS_ + h] = (v > 20.f) ? v : log1pf(expf(v));
        }
    }
}

// ---------------- SSD phase 1: per-chunk cumdecay + P = mask(C·B^T)·scale ----------------
__global__ __launch_bounds__(256) void ssd_phase1(const float* __restrict__ bmat,
                                                  const float* __restrict__ cmat,
                                                  const float* __restrict__ dtb,
                                                  const float* __restrict__ log_a,
                                                  float* __restrict__ pbuf,
                                                  float* __restrict__ eAbuf,
                                                  float* __restrict__ wbuf,
                                                  float* __restrict__ cdecay) {
    __shared__ float sBt[STATE_][Q_+1];   // [n][s]
    __shared__ float sCt[STATE_][Q_+1];   // [n][t]
    __shared__ float sA[Q_];
    __shared__ float sDt[Q_];
    const int tid = threadIdx.x;
    const int chunk = blockIdx.x;
    const int bh = chunk / NC_;
    const int ck = chunk - bh * NC_;
    const int b = bh >> 3, h = bh & 7;
    const int m0 = b * L_ + ck * Q_;

    if (tid < 64) {                // wave 0: inclusive prefix scan of dt*a
        float dt = dtb[(size_t)(m0 + tid) * HEADS_ + h];
        float a = -expf(log_a[h]);
        float x = dt * a;
#pragma unroll
        for (int off = 1; off < 64; off <<= 1) {
            float v = __shfl_up(x, off, 64);
            if (tid >= off) x += v;
        }
        float Alast = __shfl(x, 63, 64);
        sA[tid] = x;
        sDt[tid] = dt;
        eAbuf[(size_t)(m0 + tid) * HEADS_ + h] = expf(x);
        wbuf[(size_t)chunk * Q_ + tid] = expf(Alast - x) * dt;
        if (tid == 0) cdecay[chunk] = expf(Alast);
    }
#pragma unroll
    for (int l = 0; l < 4; ++l) {     // stage B,C transposed (k-major)
        int q = tid + l * 256;
        int s = q >> 4;
        int n0 = (q & 15) * 4;
        float4 bv = *(const float4*)&bmat[(size_t)(m0+s)*HS_ + h*STATE_ + n0];
        float4 cv = *(const float4*)&cmat[(size_t)(m0+s)*HS_ + h*STATE_ + n0];
        sBt[n0+0][s] = bv.x; sBt[n0+1][s] = bv.y; sBt[n0+2][s] = bv.z; sBt[n0+3][s] = bv.w;
        sCt[n0+0][s] = cv.x; sCt[n0+1][s] = cv.y; sCt[n0+2][s] = cv.z; sCt[n0+3][s] = cv.w;
    }
    __syncthreads();
    const int tx = tid & 15, ty = tid >> 4;
    float g[4][4];
#pragma unroll
    for (int i = 0; i < 4; ++i)
#pragma unroll
        for (int j = 0; j < 4; ++j) g[i][j] = 0.f;
    for (int n = 0; n < STATE_; ++n) {
        float cv[4], bv[4];
#pragma unroll
        for (int i = 0; i < 4; ++i) cv[i] = sCt[n][ty*4+i];
#pragma unroll
        for (int j = 0; j < 4; ++j) bv[j] = sBt[n][tx*4+j];
#pragma unroll
        for (int i = 0; i < 4; ++i)
#pragma unroll
            for (int j = 0; j < 4; ++j) g[i][j] += cv[i] * bv[j];
    }
#pragma unroll
    for (int i = 0; i < 4; ++i) {
        int t = ty*4 + i;
        float At = sA[t];
        float o[4];
#pragma unroll
        for (int j = 0; j < 4; ++j) {
            int s = tx*4 + j;
            o[j] = (t >= s) ? g[i][j] * expf(At - sA[s]) * sDt[s] : 0.f;
        }
        *(float4*)&pbuf[((size_t)chunk * Q_ + t) * Q_ + tx*4] = make_float4(o[0],o[1],o[2],o[3]);
    }
}

// ---------------- SSD phase 2: Y_intra = P·X ; S_local = (w·B)^T·X ----------------
__global__ __launch_bounds__(256) void ssd_phase2(const float* __restrict__ bmat,
                                                  const float* __restrict__ xconv,
                                                  const float* __restrict__ pbuf,
                                                  const float* __restrict__ wbuf,
                                                  float* __restrict__ ybuf,
                                                  float* __restrict__ sloc) {
    __shared__ float sPt[Q_][Q_+1];       // [s][t]
    __shared__ float sBw[Q_][STATE_+1];   // [s][n] (scaled)
    __shared__ float sX[Q_][Q_+4];        // [s][p-tile]
    const int tid = threadIdx.x;
    const int chunk = blockIdx.x;
    const int bh = chunk / NC_;
    const int ck = chunk - bh * NC_;
    const int b = bh >> 3, h = bh & 7;
    const int m0 = b * L_ + ck * Q_;

#pragma unroll
    for (int l = 0; l < 4; ++l) {
        int q = tid + l * 256;
        int t = q >> 4;
        int s0 = (q & 15) * 4;
        float4 pv = *(const float4*)&pbuf[((size_t)chunk*Q_ + t)*Q_ + s0];
        sPt[s0+0][t] = pv.x; sPt[s0+1][t] = pv.y; sPt[s0+2][t] = pv.z; sPt[s0+3][t] = pv.w;
        int s = t;            // same decomposition for B staging
        int n0 = s0;
        float ws = wbuf[(size_t)chunk * Q_ + s];
        float4 bv = *(const float4*)&bmat[(size_t)(m0+s)*HS_ + h*STATE_ + n0];
        sBw[s][n0+0] = bv.x * ws; sBw[s][n0+1] = bv.y * ws;
        sBw[s][n0+2] = bv.z * ws; sBw[s][n0+3] = bv.w * ws;
    }
    const int tx = tid & 15, ty = tid >> 4;
    for (int pt = 0; pt < 4; ++pt) {
        int p0 = pt * 64;
        __syncthreads();
#pragma unroll
        for (int l = 0; l < 4; ++l) {
            int q = tid + l * 256;
            int s = q >> 4;
            int pp = (q & 15) * 4;
            *(float4*)&sX[s][pp] = *(const float4*)&xconv[(size_t)(m0+s)*INNER_ + h*HDIM_ + p0 + pp];
        }
        __syncthreads();
        float accY[4][4], accS[4][4];
#pragma unroll
        for (int i = 0; i < 4; ++i)
#pragma unroll
            for (int j = 0; j < 4; ++j) { accY[i][j] = 0.f; accS[i][j] = 0.f; }
        for (int s = 0; s < Q_; ++s) {
            float pv[4], bv[4];
#pragma unroll
            for (int i = 0; i < 4; ++i) { pv[i] = sPt[s][ty*4+i]; bv[i] = sBw[s][ty*4+i]; }
            float4 xv = *(const float4*)&sX[s][tx*4];
            float xq[4] = {xv.x, xv.y, xv.z, xv.w};
#pragma unroll
            for (int i = 0; i < 4; ++i)
#pragma unroll
                for (int j = 0; j < 4; ++j) {
                    accY[i][j] += pv[i] * xq[j];
                    accS[i][j] += bv[i] * xq[j];
                }
        }
#pragma unroll
        for (int i = 0; i < 4; ++i) {
            int t = ty*4 + i;       // also the n index for S_local
            *(float4*)&ybuf[(size_t)(m0+t)*INNER_ + h*HDIM_ + p0 + tx*4] =
                make_float4(accY[i][0], accY[i][1], accY[i][2], accY[i][3]);
            *(float4*)&sloc[((size_t)chunk*STATE_ + t)*HDIM_ + p0 + tx*4] =
                make_float4(accS[i][0], accS[i][1], accS[i][2], accS[i][3]);
        }
    }
}

// ---------------- SSD phase B: sequential inter-chunk state recurrence ----------------
__global__ __launch_bounds__(256) void chunk_scan_k(float* __restrict__ sloc,
                                                    const float* __restrict__ cdecay) {
    int bh = blockIdx.x >> 6;
    int el = (blockIdx.x & 63) * 256 + threadIdx.x;  // 0..16383 within (n,p)
    float s = 0.f;
    for (int c = 0; c < NC_; ++c) {
        size_t chunk = (size_t)bh * NC_ + c;
        float* ptr = sloc + chunk * (size_t)(STATE_*HDIM_) + el;
        float tmp = *ptr;
        *ptr = s;                    // becomes S_in for this chunk
        s = cdecay[chunk] * s + tmp;
    }
}

// ---------------- SSD phase 3: y += exp(A_t)·(C·S_in) + d·x ; GN partial sums ----------------
__global__ __launch_bounds__(256) void ssd_phase3(const float* __restrict__ cmat,
                                                  const float* __restrict__ xconv,
                                                  const float* __restrict__ sloc,
                                                  const float* __restrict__ eAbuf,
                                                  const float* __restrict__ dparam,
                                                  float* __restrict__ ybuf,
                                                  float* __restrict__ gstats) {
    __shared__ float sCt[STATE_][Q_+1];   // [n][t]
    __shared__ float sS[STATE_][Q_+4];    // [n][p-tile]
    __shared__ float red[512];
    const int tid = threadIdx.x;
    const int chunk = blockIdx.x;
    const int bh = chunk / NC_;
    const int ck = chunk - bh * NC_;
    const int b = bh >> 3, h = bh & 7;
    const int m0 = b * L_ + ck * Q_;

#pragma unroll
    for (int l = 0; l < 4; ++l) {
        int q = tid + l * 256;
        int t = q >> 4;
        int n0 = (q & 15) * 4;
        float4 cv = *(const float4*)&cmat[(size_t)(m0+t)*HS_ + h*STATE_ + n0];
        sCt[n0+0][t] = cv.x; sCt[n0+1][t] = cv.y; sCt[n0+2][t] = cv.z; sCt[n0+3][t] = cv.w;
    }
    const int tx = tid & 15, ty = tid >> 4;
    const float d = dparam[h];
    float lsum = 0.f, lsq = 0.f;
    for (int pt = 0; pt < 4; ++pt) {
        int p0 = pt * 64;
        __syncthreads();
#pragma unroll
        for (int l = 0; l < 4; ++l) {
            int q = tid + l * 256;
            int n = q >> 4;
            int pp = (q & 15) * 4;
            *(float4*)&sS[n][pp] = *(const float4*)&sloc[((size_t)chunk*STATE_ + n)*HDIM_ + p0 + pp];
        }
        __syncthreads();
        float acc[4][4];
#pragma unroll
        for (int i = 0; i < 4; ++i)
#pragma unroll
            for (int j = 0; j < 4; ++j) acc[i][j] = 0.f;
        for (int n = 0; n < STATE_; ++n) {
            float cv[4];
#pragma unroll
            for (int i = 0; i < 4; ++i) cv[i] = sCt[n][ty*4+i];
            float4 sv = *(const float4*)&sS[n][tx*4];
            float sq[4] = {sv.x, sv.y, sv.z, sv.w};
#pragma unroll
            for (int i = 0; i < 4; ++i)
#pragma unroll
                for (int j = 0; j < 4; ++j) acc[i][j] += cv[i] * sq[j];
        }
#pragma unroll
        for (int i = 0; i < 4; ++i) {
            int t = ty*4 + i;
            float eA = eAbuf[(size_t)(m0+t)*HEADS_ + h];
            size_t off = (size_t)(m0+t)*INNER_ + h*HDIM_ + p0 + tx*4;
            float4 yin = *(const float4*)&ybuf[off];
            float4 xv  = *(const float4*)&xconv[off];
            float4 o;
            o.x = yin.x + eA*acc[i][0] + d*xv.x;
            o.y = yin.y + eA*acc[i][1] + d*xv.y;
            o.z = yin.z + eA*acc[i][2] + d*xv.z;
            o.w = yin.w + eA*acc[i][3] + d*xv.w;
            *(float4*)&ybuf[off] = o;
            lsum += o.x + o.y + o.z + o.w;
            lsq  += o.x*o.x + o.y*o.y + o.z*o.z + o.w*o.w;
        }
    }
    __syncthreads();
    red[tid] = lsum; red[256+tid] = lsq;
    __syncthreads();
    for (int st = 128; st > 0; st >>= 1) {
        if (tid < st) { red[tid] += red[tid+st]; red[256+tid] += red[256+tid+st]; }
        __syncthreads();
    }
    if (tid == 0) {
        atomicAdd(&gstats[bh*2+0], red[0]);
        atomicAdd(&gstats[bh*2+1], red[256]);
    }
}

// ---------------- GroupNorm finalize + gate: g = (norm(y)*w+b) * silu(z) ----------------
__global__ __launch_bounds__(256) void gn_gate_k(const float* __restrict__ ybuf,
                                                 const float* __restrict__ zbuf,
                                                 const float* __restrict__ gstats,
                                                 const float* __restrict__ gnw,
                                                 const float* __restrict__ gnb,
                                                 float* __restrict__ g) {
    int idx = blockIdx.x * 256 + threadIdx.x;
    int c = (idx & (INNER_/4 - 1)) * 4;
    int m = idx >> 9;
    int bh = (m >> 11) * HEADS_ + (c >> 8);   // m/L_ , c/HDIM_
    const float cnt = (float)(L_ * HDIM_);
    float mean = gstats[bh*2] / cnt;
    float var  = gstats[bh*2+1] / cnt - mean*mean;
    float rstd = rsqrtf(var + EPS_);
    float4 yv = *(const float4*)&ybuf[(size_t)m*INNER_ + c];
    float4 zv = *(const float4*)&zbuf[(size_t)m*INNER_ + c];
    float4 wv = *(const float4*)&gnw[c];
    float4 bv = *(const float4*)&gnb[c];
    float4 o;
    o.x = ((yv.x - mean)*rstd*wv.x + bv.x) * siluf(zv.x);
    o.y = ((yv.y - mean)*rstd*wv.y + bv.y) * siluf(zv.y);
    o.z = ((yv.z - mean)*rstd*wv.z + bv.z) * siluf(zv.z);
    o.w = ((yv.w - mean)*rstd*wv.w + bv.w) * siluf(zv.w);
    *(float4*)&g[(size_t)m*INNER_ + c] = o;
}

// ---------------- launch ----------------
extern "C" void kernel_launch(void* const* d_in, const int* in_sizes, int n_in,
                              void* d_out, int out_size, void* d_ws, size_t ws_size,
                              hipStream_t stream) {
    const float* input  = (const float*)d_in[0];
    const float* Wx     = (const float*)d_in[1];
    const float* Wz     = (const float*)d_in[2];
    const float* conv_w = (const float*)d_in[3];
    const float* conv_b = (const float*)d_in[4];
    const float* Wb     = (const float*)d_in[5];
    const float* Wc     = (const float*)d_in[6];
    const float* Wdt    = (const float*)d_in[7];
    const float* b_dt   = (const float*)d_in[8];
    const float* log_a  = (const float*)d_in[9];
    const float* d_par  = (const float*)d_in[10];
    const float* gn_w   = (const float*)d_in[11];
    const float* gn_b   = (const float*)d_in[12];
    const float* Wout   = (const float*)d_in[13];
    float* out = (float*)d_out;

    float* ws = (float*)d_ws;
    size_t off = 0;
    auto alloc = [&](size_t n) { float* p = ws + off; off += (n + 63) & ~(size_t)63; return p; };
    float* xpre  = alloc((size_t)M_*INNER_);
    float* zbuf  = alloc((size_t)M_*INNER_);
    float* xconv = alloc((size_t)M_*INNER_);
    float* bmat  = alloc((size_t)M_*HS_);
    float* cmat  = alloc((size_t)M_*HS_);
    float* dtb   = alloc((size_t)M_*HEADS_);
    float* eAb   = alloc((size_t)M_*HEADS_);
    float* wbuf  = alloc((size_t)NCHUNK_*Q_);
    float* ybuf  = alloc((size_t)M_*INNER_);
    float* pbuf  = alloc((size_t)NCHUNK_*Q_*Q_);
    float* sloc  = alloc((size_t)NCHUNK_*STATE_*HDIM_);
    float* cdec  = alloc((size_t)NCHUNK_);
    float* gstat = alloc((size_t)2*B_*HEADS_);
    float* gbuf  = xpre;   // xpre dead after conv; reuse for gated activations

    dim3 blk(256);
    sgemm_nt<<<dim3(INNER_/128, M_/128), blk, 0, stream>>>(input, Wx, xpre, DIM_, INNER_);
    sgemm_nt<<<dim3(INNER_/128, M_/128), blk, 0, stream>>>(input, Wz, zbuf, DIM_, INNER_);
    conv_silu_k<<<(M_*(INNER_/4))/256, blk, 0, stream>>>(xpre, conv_w, conv_b, xconv);
    sgemm_nt<<<dim3(HS_/128, M_/128), blk, 0, stream>>>(xconv, Wb, bmat, INNER_, HS_);
    sgemm_nt<<<dim3(HS_/128, M_/128), blk, 0, stream>>>(xconv, Wc, cmat, INNER_, HS_);
    dt_proj_k<<<M_/4, blk, 0, stream>>>(xconv, Wdt, b_dt, dtb);
    ssd_phase1<<<NCHUNK_, blk, 0, stream>>>(bmat, cmat, dtb, log_a, pbuf, eAb, wbuf, cdec);
    ssd_phase2<<<NCHUNK_, blk, 0, stream>>>(bmat, xconv, pbuf, wbuf, ybuf, sloc);
    chunk_scan_k<<<B_*HEADS_*64, blk, 0, stream>>>(sloc, cdec);
    hipMemsetAsync(gstat, 0, 2*B_*HEADS_*sizeof(float), stream);
    ssd_phase3<<<NCHUNK_, blk, 0, stream>>>(cmat, xconv, sloc, eAb, d_par, ybuf, gstat);
    gn_gate_k<<<(M_*(INNER_/4))/256, blk, 0, stream>>>(ybuf, zbuf, gstat, gn_w, gn_b, gbuf);
    sgemm_nt<<<dim3(DIM_/128, M_/128), blk, 0, stream>>>(gbuf, Wout, out, INNER_, DIM_);
}

// Round 2
// 443.364 us; speedup vs baseline: 3.2160x; 3.2160x over previous
//
#include <hip/hip_runtime.h>
#include <math.h>

// ---------------- problem constants ----------------
#define DIM_   1024
#define STATE_ 64
#define HEADS_ 8
#define INNER_ 2048
#define HDIM_  256          // INNER/HEADS
#define B_     2
#define L_     2048
#define M_     (B_*L_)      // 4096 rows total
#define EPS_   1e-5f
#define Q_     64           // SSD chunk length
#define NC_    (L_/Q_)      // 32 chunks per sequence
#define NCHUNK_ (B_*HEADS_*NC_)  // 512 chunk-blocks
#define BCS_   1024         // combined B|C projection row stride

typedef _Float16 f16;
typedef __attribute__((ext_vector_type(8))) _Float16 half8;
typedef __attribute__((ext_vector_type(4))) _Float16 half4;
typedef __attribute__((ext_vector_type(4))) float    f32x4;

__device__ __forceinline__ float siluf(float x) { return x / (1.f + expf(-x)); }

__device__ __forceinline__ void gload_lds16(const void* g, void* l) {
    __builtin_amdgcn_global_load_lds((const __attribute__((address_space(1))) void*)g,
                                     (__attribute__((address_space(3))) void*)l, 16, 0, 0);
}

// ---------------- fp32 -> f16 cast ----------------
__global__ __launch_bounds__(256) void cast_h(const float* __restrict__ in,
                                              f16* __restrict__ out, int n4) {
    int i = blockIdx.x * 256 + threadIdx.x;
    if (i < n4) {
        float4 v = *(const float4*)&in[i * 4];
        half4 o;
        o[0] = (f16)v.x; o[1] = (f16)v.y; o[2] = (f16)v.z; o[3] = (f16)v.w;
        *(half4*)&out[i * 4] = o;
    }
}

// ---------------- f16 MFMA GEMM: C[M x N] = A[M x K] * W[N x K]^T ----------------
// m97 structure: 128x128 tile, BK=32, 4 waves (2x2), 4x4 16x16x32 frags/wave,
// global_load_lds(16B) staging with pre-swizzled source + swizzled ds_read_b128.
// swizzle: phys 16B-slot p = row*4 + (kg ^ f(row)), f(row)=(row>>1)&3 (involution).
template<bool OUTF16>
__global__ __launch_bounds__(256) void hgemm(const f16* __restrict__ A,
                                             const f16* __restrict__ W,
                                             void* __restrict__ Cout,
                                             int K, int N) {
    __shared__ f16 sA[4096];   // 128 rows x 32 k
    __shared__ f16 sW[4096];
    const int tid  = threadIdx.x;
    const int wid  = tid >> 6;
    const int lane = tid & 63;
    const int bm = blockIdx.y * 128;
    const int bn = blockIdx.x * 128;
    const int wr = wid >> 1, wc = wid & 1;
    const int r  = lane & 15, kg = lane >> 4;

    // staging: 512 slots per tile, thread t handles phys slots t and t+256
    const int p0 = tid,      row0 = p0 >> 2, kg0 = ((p0 & 3) ^ ((row0 >> 1) & 3)) * 8;
    const int p1 = tid + 256, row1 = p1 >> 2, kg1 = ((p1 & 3) ^ ((row1 >> 1) & 3)) * 8;
    const f16* gA0 = A + (size_t)(bm + row0) * K + kg0;
    const f16* gA1 = A + (size_t)(bm + row1) * K + kg1;
    const f16* gW0 = W + (size_t)(bn + row0) * K + kg0;
    const f16* gW1 = W + (size_t)(bn + row1) * K + kg1;
    f16* lA0 = &sA[wid * 512];          // wave-uniform LDS bases (+lane*16B implicit)
    f16* lA1 = &sA[2048 + wid * 512];
    f16* lW0 = &sW[wid * 512];
    f16* lW1 = &sW[2048 + wid * 512];

    // fragment read offsets (swizzled), k-invariant
    int aoff[4], boff[4];
#pragma unroll
    for (int m = 0; m < 4; ++m) {
        int arow = wr * 64 + m * 16 + r;
        aoff[m] = arow * 32 + ((kg ^ ((arow >> 1) & 3)) << 3);
        int wrow = wc * 64 + m * 16 + r;
        boff[m] = wrow * 32 + ((kg ^ ((wrow >> 1) & 3)) << 3);
    }

    f32x4 acc[4][4];
#pragma unroll
    for (int m = 0; m < 4; ++m)
#pragma unroll
        for (int n = 0; n < 4; ++n) acc[m][n] = (f32x4)0.f;

    for (int k0 = 0; k0 < K; k0 += 32) {
        gload_lds16(gA0 + k0, lA0);
        gload_lds16(gA1 + k0, lA1);
        gload_lds16(gW0 + k0, lW0);
        gload_lds16(gW1 + k0, lW1);
        __syncthreads();                 // drains vmcnt: tiles ready
        half8 av[4], bv[4];
#pragma unroll
        for (int m = 0; m < 4; ++m) av[m] = *(const half8*)&sA[aoff[m]];
#pragma unroll
        for (int n = 0; n < 4; ++n) bv[n] = *(const half8*)&sW[boff[n]];
#pragma unroll
        for (int m = 0; m < 4; ++m)
#pragma unroll
            for (int n = 0; n < 4; ++n)
                acc[m][n] = __builtin_amdgcn_mfma_f32_16x16x32_f16(av[m], bv[n], acc[m][n], 0, 0, 0);
        __syncthreads();                 // all reads done before next overwrite
    }

    // C/D layout: col = lane&15, row = (lane>>4)*4 + j  [m89-verified]
#pragma unroll
    for (int m = 0; m < 4; ++m)
#pragma unroll
        for (int n = 0; n < 4; ++n) {
            int row0o = bm + wr * 64 + m * 16 + kg * 4;
            int col   = bn + wc * 64 + n * 16 + r;
#pragma unroll
            for (int j = 0; j < 4; ++j) {
                if (OUTF16) ((f16*)Cout)[(size_t)(row0o + j) * N + col] = (f16)acc[m][n][j];
                else        ((float*)Cout)[(size_t)(row0o + j) * N + col] = acc[m][n][j];
            }
        }
}

// ---------------- causal depthwise conv (K=4) + bias + SiLU (f16 in/out) ----------------
__global__ __launch_bounds__(256) void conv_silu_h(const f16* __restrict__ xpre,
                                                   const float* __restrict__ cw,
                                                   const float* __restrict__ cb,
                                                   f16* __restrict__ xc) {
    int idx = blockIdx.x * 256 + threadIdx.x;      // over M_*INNER_/8
    int c8 = (idx & (INNER_/8 - 1)) * 8;
    int m = idx >> 8;
    int t = m & (L_ - 1);
    float acc[8];
    float4 wv[8];
#pragma unroll
    for (int j = 0; j < 8; ++j) { acc[j] = cb[c8 + j]; wv[j] = *(const float4*)&cw[(c8 + j) * 4]; }
#pragma unroll
    for (int k = 0; k < 4; ++k) {
        int tt = t - 3 + k;
        if (tt >= 0) {
            half8 xv = *(const half8*)&xpre[(size_t)(m - 3 + k) * INNER_ + c8];
#pragma unroll
            for (int j = 0; j < 8; ++j) acc[j] += (float)xv[j] * ((const float*)&wv[j])[k];
        }
    }
    half8 o;
#pragma unroll
    for (int j = 0; j < 8; ++j) o[j] = (f16)siluf(acc[j]);
    *(half8*)&xc[(size_t)m * INNER_ + c8] = o;
}

// ---------------- dt = softplus(x @ Wdt^T + b_dt), one wave per row ----------------
__global__ __launch_bounds__(256) void dt_proj_k(const f16* __restrict__ xc,
                                                 const float* __restrict__ Wdt,
                                                 const float* __restrict__ bdt,
                                                 float* __restrict__ dtb) {
    int row = (blockIdx.x * 256 + threadIdx.x) >> 6;
    int lane = threadIdx.x & 63;
    const f16* xr = xc + (size_t)row * INNER_;
    float p[HEADS_];
#pragma unroll
    for (int h = 0; h < HEADS_; ++h) p[h] = 0.f;
    for (int k = lane * 8; k < INNER_; k += 512) {
        half8 xv = *(const half8*)&xr[k];
        float xf[8];
#pragma unroll
        for (int j = 0; j < 8; ++j) xf[j] = (float)xv[j];
#pragma unroll
        for (int h = 0; h < HEADS_; ++h) {
            float4 w0 = *(const float4*)&Wdt[h * INNER_ + k];
            float4 w1 = *(const float4*)&Wdt[h * INNER_ + k + 4];
            p[h] += xf[0]*w0.x + xf[1]*w0.y + xf[2]*w0.z + xf[3]*w0.w
                  + xf[4]*w1.x + xf[5]*w1.y + xf[6]*w1.z + xf[7]*w1.w;
        }
    }
#pragma unroll
    for (int h = 0; h < HEADS_; ++h)
#pragma unroll
        for (int off = 32; off > 0; off >>= 1)
            p[h] += __shfl_down(p[h], off, 64);
    if (lane == 0) {
#pragma unroll
        for (int h = 0; h < HEADS_; ++h) {
            float v = p[h] + bdt[h];
            dtb[(size_t)row * HEADS_ + h] = (v > 20.f) ? v : log1pf(expf(v));
        }
    }
}

// ---------------- SSD phase 1: per-chunk cumdecay + P = mask(C·B^T)·scale ----------------
__global__ __launch_bounds__(256) void ssd_phase1(const float* __restrict__ bc,
                                                  const float* __restrict__ dtb,
                                                  const float* __restrict__ log_a,
                                                  float* __restrict__ pbuf,
                                                  float* __restrict__ eAbuf,
                                                  float* __restrict__ wbuf,
                                                  float* __restrict__ cdecay) {
    __shared__ float sBt[STATE_][Q_+1];   // [n][s]
    __shared__ float sCt[STATE_][Q_+1];   // [n][t]
    __shared__ float sA[Q_];
    __shared__ float sDt[Q_];
    const int tid = threadIdx.x;
    const int chunk = blockIdx.x;
    const int bh = chunk / NC_;
    const int ck = chunk - bh * NC_;
    const int b = bh >> 3, h = bh & 7;
    const int m0 = b * L_ + ck * Q_;

    if (tid < 64) {                // wave 0: inclusive prefix scan of dt*a
        float dt = dtb[(size_t)(m0 + tid) * HEADS_ + h];
        float a = -expf(log_a[h]);
        float x = dt * a;
#pragma unroll
        for (int off = 1; off < 64; off <<= 1) {
            float v = __shfl_up(x, off, 64);
            if (tid >= off) x += v;
        }
        float Alast = __shfl(x, 63, 64);
        sA[tid] = x;
        sDt[tid] = dt;
        eAbuf[(size_t)(m0 + tid) * HEADS_ + h] = expf(x);
        wbuf[(size_t)chunk * Q_ + tid] = expf(Alast - x) * dt;
        if (tid == 0) cdecay[chunk] = expf(Alast);
    }
#pragma unroll
    for (int l = 0; l < 4; ++l) {     // stage B,C transposed (k-major)
        int q = tid + l * 256;
        int s = q >> 4;
        int n0 = (q & 15) * 4;
        float4 bv = *(const float4*)&bc[(size_t)(m0+s)*BCS_ + h*STATE_ + n0];
        float4 cv = *(const float4*)&bc[(size_t)(m0+s)*BCS_ + 512 + h*STATE_ + n0];
        sBt[n0+0][s] = bv.x; sBt[n0+1][s] = bv.y; sBt[n0+2][s] = bv.z; sBt[n0+3][s] = bv.w;
        sCt[n0+0][s] = cv.x; sCt[n0+1][s] = cv.y; sCt[n0+2][s] = cv.z; sCt[n0+3][s] = cv.w;
    }
    __syncthreads();
    const int tx = tid & 15, ty = tid >> 4;
    float g[4][4];
#pragma unroll
    for (int i = 0; i < 4; ++i)
#pragma unroll
        for (int j = 0; j < 4; ++j) g[i][j] = 0.f;
    for (int n = 0; n < STATE_; ++n) {
        float cv[4], bv[4];
#pragma unroll
        for (int i = 0; i < 4; ++i) cv[i] = sCt[n][ty*4+i];
#pragma unroll
        for (int j = 0; j < 4; ++j) bv[j] = sBt[n][tx*4+j];
#pragma unroll
        for (int i = 0; i < 4; ++i)
#pragma unroll
            for (int j = 0; j < 4; ++j) g[i][j] += cv[i] * bv[j];
    }
#pragma unroll
    for (int i = 0; i < 4; ++i) {
        int t = ty*4 + i;
        float At = sA[t];
        float o[4];
#pragma unroll
        for (int j = 0; j < 4; ++j) {
            int s = tx*4 + j;
            o[j] = (t >= s) ? g[i][j] * expf(At - sA[s]) * sDt[s] : 0.f;
        }
        *(float4*)&pbuf[((size_t)chunk * Q_ + t) * Q_ + tx*4] = make_float4(o[0],o[1],o[2],o[3]);
    }
}

// ---------------- SSD phase 2: Y_intra = P·X ; S_local = (w·B)^T·X ----------------
__global__ __launch_bounds__(256) void ssd_phase2(const float* __restrict__ bc,
                                                  const f16* __restrict__ xch,
                                                  const float* __restrict__ pbuf,
                                                  const float* __restrict__ wbuf,
                                                  float* __restrict__ ybuf,
                                                  float* __restrict__ sloc) {
    __shared__ float sPt[Q_][Q_+1];       // [s][t]
    __shared__ float sBw[Q_][STATE_+1];   // [s][n] (scaled)
    __shared__ float sX[Q_][Q_+4];        // [s][p-tile]
    const int tid = threadIdx.x;
    const int chunk = blockIdx.x;
    const int bh = chunk / NC_;
    const int ck = chunk - bh * NC_;
    const int b = bh >> 3, h = bh & 7;
    const int m0 = b * L_ + ck * Q_;

#pragma unroll
    for (int l = 0; l < 4; ++l) {
        int q = tid + l * 256;
        int t = q >> 4;
        int s0 = (q & 15) * 4;
        float4 pv = *(const float4*)&pbuf[((size_t)chunk*Q_ + t)*Q_ + s0];
        sPt[s0+0][t] = pv.x; sPt[s0+1][t] = pv.y; sPt[s0+2][t] = pv.z; sPt[s0+3][t] = pv.w;
        int s = t;            // same decomposition for B staging
        int n0 = s0;
        float ws = wbuf[(size_t)chunk * Q_ + s];
        float4 bv = *(const float4*)&bc[(size_t)(m0+s)*BCS_ + h*STATE_ + n0];
        sBw[s][n0+0] = bv.x * ws; sBw[s][n0+1] = bv.y * ws;
        sBw[s][n0+2] = bv.z * ws; sBw[s][n0+3] = bv.w * ws;
    }
    const int tx = tid & 15, ty = tid >> 4;
    for (int pt = 0; pt < 4; ++pt) {
        int p0 = pt * 64;
        __syncthreads();
#pragma unroll
        for (int l = 0; l < 2; ++l) {
            int q = tid + l * 256;       // 0..511
            int s = q >> 3;              // 0..63
            int pp = (q & 7) * 8;
            half8 xv = *(const half8*)&xch[(size_t)(m0+s)*INNER_ + h*HDIM_ + p0 + pp];
#pragma unroll
            for (int j = 0; j < 8; ++j) sX[s][pp+j] = (float)xv[j];
        }
        __syncthreads();
        float accY[4][4], accS[4][4];
#pragma unroll
        for (int i = 0; i < 4; ++i)
#pragma unroll
            for (int j = 0; j < 4; ++j) { accY[i][j] = 0.f; accS[i][j] = 0.f; }
        for (int s = 0; s < Q_; ++s) {
            float pv[4], bv[4];
#pragma unroll
            for (int i = 0; i < 4; ++i) { pv[i] = sPt[s][ty*4+i]; bv[i] = sBw[s][ty*4+i]; }
            float4 xv = *(const float4*)&sX[s][tx*4];
            float xq[4] = {xv.x, xv.y, xv.z, xv.w};
#pragma unroll
            for (int i = 0; i < 4; ++i)
#pragma unroll
                for (int j = 0; j < 4; ++j) {
                    accY[i][j] += pv[i] * xq[j];
                    accS[i][j] += bv[i] * xq[j];
                }
        }
#pragma unroll
        for (int i = 0; i < 4; ++i) {
            int t = ty*4 + i;       // also the n index for S_local
            *(float4*)&ybuf[(size_t)(m0+t)*INNER_ + h*HDIM_ + p0 + tx*4] =
                make_float4(accY[i][0], accY[i][1], accY[i][2], accY[i][3]);
            *(float4*)&sloc[((size_t)chunk*STATE_ + t)*HDIM_ + p0 + tx*4] =
                make_float4(accS[i][0], accS[i][1], accS[i][2], accS[i][3]);
        }
    }
}

// ---------------- SSD phase B: sequential inter-chunk state recurrence ----------------
__global__ __launch_bounds__(256) void chunk_scan_k(float* __restrict__ sloc,
                                                    const float* __restrict__ cdecay) {
    int bh = blockIdx.x >> 6;
    int el = (blockIdx.x & 63) * 256 + threadIdx.x;  // 0..16383 within (n,p)
    float s = 0.f;
    for (int c = 0; c < NC_; ++c) {
        size_t chunk = (size_t)bh * NC_ + c;
        float* ptr = sloc + chunk * (size_t)(STATE_*HDIM_) + el;
        float tmp = *ptr;
        *ptr = s;                    // becomes S_in for this chunk
        s = cdecay[chunk] * s + tmp;
    }
}

// ---------------- SSD phase 3: y += exp(A_t)·(C·S_in) + d·x ; GN partial sums ----------------
__global__ __launch_bounds__(256) void ssd_phase3(const float* __restrict__ bc,
                                                  const f16* __restrict__ xch,
                                                  const float* __restrict__ sloc,
                                                  const float* __restrict__ eAbuf,
                                                  const float* __restrict__ dparam,
                                                  float* __restrict__ ybuf,
                                                  float* __restrict__ gstats) {
    __shared__ float sCt[STATE_][Q_+1];   // [n][t]
    __shared__ float sS[STATE_][Q_+4];    // [n][p-tile]
    __shared__ float red[512];
    const int tid = threadIdx.x;
    const int chunk = blockIdx.x;
    const int bh = chunk / NC_;
    const int ck = chunk - bh * NC_;
    const int b = bh >> 3, h = bh & 7;
    const int m0 = b * L_ + ck * Q_;

#pragma unroll
    for (int l = 0; l < 4; ++l) {
        int q = tid + l * 256;
        int t = q >> 4;
        int n0 = (q & 15) * 4;
        float4 cv = *(const float4*)&bc[(size_t)(m0+t)*BCS_ + 512 + h*STATE_ + n0];
        sCt[n0+0][t] = cv.x; sCt[n0+1][t] = cv.y; sCt[n0+2][t] = cv.z; sCt[n0+3][t] = cv.w;
    }
    const int tx = tid & 15, ty = tid >> 4;
    const float d = dparam[h];
    float lsum = 0.f, lsq = 0.f;
    for (int pt = 0; pt < 4; ++pt) {
        int p0 = pt * 64;
        __syncthreads();
#pragma unroll
        for (int l = 0; l < 4; ++l) {
            int q = tid + l * 256;
            int n = q >> 4;
            int pp = (q & 15) * 4;
            *(float4*)&sS[n][pp] = *(const float4*)&sloc[((size_t)chunk*STATE_ + n)*HDIM_ + p0 + pp];
        }
        __syncthreads();
        float acc[4][4];
#pragma unroll
        for (int i = 0; i < 4; ++i)
#pragma unroll
            for (int j = 0; j < 4; ++j) acc[i][j] = 0.f;
        for (int n = 0; n < STATE_; ++n) {
            float cv[4];
#pragma unroll
            for (int i = 0; i < 4; ++i) cv[i] = sCt[n][ty*4+i];
            float4 sv = *(const float4*)&sS[n][tx*4];
            float sq[4] = {sv.x, sv.y, sv.z, sv.w};
#pragma unroll
            for (int i = 0; i < 4; ++i)
#pragma unroll
                for (int j = 0; j < 4; ++j) acc[i][j] += cv[i] * sq[j];
        }
#pragma unroll
        for (int i = 0; i < 4; ++i) {
            int t = ty*4 + i;
            float eA = eAbuf[(size_t)(m0+t)*HEADS_ + h];
            size_t off = (size_t)(m0+t)*INNER_ + h*HDIM_ + p0 + tx*4;
            float4 yin = *(const float4*)&ybuf[off];
            half4 xv4 = *(const half4*)&xch[off];
            float4 o;
            o.x = yin.x + eA*acc[i][0] + d*(float)xv4[0];
            o.y = yin.y + eA*acc[i][1] + d*(float)xv4[1];
            o.z = yin.z + eA*acc[i][2] + d*(float)xv4[2];
            o.w = yin.w + eA*acc[i][3] + d*(float)xv4[3];
            *(float4*)&ybuf[off] = o;
            lsum += o.x + o.y + o.z + o.w;
            lsq  += o.x*o.x + o.y*o.y + o.z*o.z + o.w*o.w;
        }
    }
    __syncthreads();
    red[tid] = lsum; red[256+tid] = lsq;
    __syncthreads();
    for (int st = 128; st > 0; st >>= 1) {
        if (tid < st) { red[tid] += red[tid+st]; red[256+tid] += red[256+tid+st]; }
        __syncthreads();
    }
    if (tid == 0) {
        atomicAdd(&gstats[bh*2+0], red[0]);
        atomicAdd(&gstats[bh*2+1], red[256]);
    }
}

// ---------------- GroupNorm finalize + gate: g = (norm(y)*w+b) * silu(z) ----------------
__global__ __launch_bounds__(256) void gn_gate_h(const float* __restrict__ ybuf,
                                                 const f16* __restrict__ zb,
                                                 const float* __restrict__ gstats,
                                                 const float* __restrict__ gnw,
                                                 const float* __restrict__ gnb,
                                                 f16* __restrict__ g) {
    int idx = blockIdx.x * 256 + threadIdx.x;    // over M_*INNER_/8
    int c8 = (idx & (INNER_/8 - 1)) * 8;
    int m = idx >> 8;
    int bh = (m >> 11) * HEADS_ + (c8 >> 8);
    const float cnt = (float)(L_ * HDIM_);
    float mean = gstats[bh*2] / cnt;
    float var  = gstats[bh*2+1] / cnt - mean*mean;
    float rstd = rsqrtf(var + EPS_);
    size_t off = (size_t)m * INNER_ + c8;
    float4 y0 = *(const float4*)&ybuf[off];
    float4 y1 = *(const float4*)&ybuf[off + 4];
    half8 zv = *(const half8*)&zb[off];
    float4 w0 = *(const float4*)&gnw[c8], w1 = *(const float4*)&gnw[c8+4];
    float4 b0 = *(const float4*)&gnb[c8], b1 = *(const float4*)&gnb[c8+4];
    float yn[8] = {y0.x, y0.y, y0.z, y0.w, y1.x, y1.y, y1.z, y1.w};
    float wv[8] = {w0.x, w0.y, w0.z, w0.w, w1.x, w1.y, w1.z, w1.w};
    float bv[8] = {b0.x, b0.y, b0.z, b0.w, b1.x, b1.y, b1.z, b1.w};
    half8 o;
#pragma unroll
    for (int j = 0; j < 8; ++j) {
        float v = (yn[j] - mean) * rstd * wv[j] + bv[j];
        o[j] = (f16)(v * siluf((float)zv[j]));
    }
    *(half8*)&g[off] = o;
}

// ---------------- launch ----------------
extern "C" void kernel_launch(void* const* d_in, const int* in_sizes, int n_in,
                              void* d_out, int out_size, void* d_ws, size_t ws_size,
                              hipStream_t stream) {
    const float* input  = (const float*)d_in[0];
    const float* Wx     = (const float*)d_in[1];
    const float* Wz     = (const float*)d_in[2];
    const float* conv_w = (const float*)d_in[3];
    const float* conv_b = (const float*)d_in[4];
    const float* Wb     = (const float*)d_in[5];
    const float* Wc     = (const float*)d_in[6];
    const float* Wdt    = (const float*)d_in[7];
    const float* b_dt   = (const float*)d_in[8];
    const float* log_a  = (const float*)d_in[9];
    const float* d_par  = (const float*)d_in[10];
    const float* gn_w   = (const float*)d_in[11];
    const float* gn_b   = (const float*)d_in[12];
    const float* Wout   = (const float*)d_in[13];
    float* out = (float*)d_out;

    float* ws = (float*)d_ws;
    size_t off = 0;
    auto alloc = [&](size_t nfloats) { float* p = ws + off; off += (nfloats + 63) & ~(size_t)63; return p; };
    f16* input_h = (f16*)alloc((size_t)M_*DIM_/2);
    f16* wx_h    = (f16*)alloc((size_t)INNER_*DIM_/2);
    f16* wz_h    = (f16*)alloc((size_t)INNER_*DIM_/2);
    f16* wbc_h   = (f16*)alloc((size_t)BCS_*INNER_/2);
    f16* wout_h  = (f16*)alloc((size_t)DIM_*INNER_/2);
    f16* xpre_h  = (f16*)alloc((size_t)M_*INNER_/2);
    f16* zbuf_h  = (f16*)alloc((size_t)M_*INNER_/2);
    f16* xconv_h = (f16*)alloc((size_t)M_*INNER_/2);
    f16* gbuf_h  = (f16*)alloc((size_t)M_*INNER_/2);
    float* bcmat = alloc((size_t)M_*BCS_);
    float* dtb   = alloc((size_t)M_*HEADS_);
    float* eAb   = alloc((size_t)M_*HEADS_);
    float* wbuf  = alloc((size_t)NCHUNK_*Q_);
    float* ybuf  = alloc((size_t)M_*INNER_);
    float* pbuf  = alloc((size_t)NCHUNK_*Q_*Q_);
    float* sloc  = alloc((size_t)NCHUNK_*STATE_*HDIM_);
    float* cdec  = alloc((size_t)NCHUNK_);
    float* gstat = alloc((size_t)2*B_*HEADS_);

    dim3 blk(256);
    auto cgrid = [](size_t n) { return dim3((unsigned)((n/4 + 255) / 256)); };

    cast_h<<<cgrid((size_t)M_*DIM_), blk, 0, stream>>>(input, input_h, M_*DIM_/4);
    cast_h<<<cgrid((size_t)INNER_*DIM_), blk, 0, stream>>>(Wx, wx_h, INNER_*DIM_/4);
    cast_h<<<cgrid((size_t)INNER_*DIM_), blk, 0, stream>>>(Wz, wz_h, INNER_*DIM_/4);
    cast_h<<<cgrid((size_t)512*INNER_), blk, 0, stream>>>(Wb, wbc_h, 512*INNER_/4);
    cast_h<<<cgrid((size_t)512*INNER_), blk, 0, stream>>>(Wc, wbc_h + (size_t)512*INNER_, 512*INNER_/4);
    cast_h<<<cgrid((size_t)DIM_*INNER_), blk, 0, stream>>>(Wout, wout_h, DIM_*INNER_/4);

    hgemm<true><<<dim3(INNER_/128, M_/128), blk, 0, stream>>>(input_h, wx_h, xpre_h, DIM_, INNER_);
    hgemm<true><<<dim3(INNER_/128, M_/128), blk, 0, stream>>>(input_h, wz_h, zbuf_h, DIM_, INNER_);
    conv_silu_h<<<(M_*(INNER_/8))/256, blk, 0, stream>>>(xpre_h, conv_w, conv_b, xconv_h);
    hgemm<false><<<dim3(BCS_/128, M_/128), blk, 0, stream>>>(xconv_h, wbc_h, bcmat, INNER_, BCS_);
    dt_proj_k<<<M_/4, blk, 0, stream>>>(xconv_h, Wdt, b_dt, dtb);
    ssd_phase1<<<NCHUNK_, blk, 0, stream>>>(bcmat, dtb, log_a, pbuf, eAb, wbuf, cdec);
    ssd_phase2<<<NCHUNK_, blk, 0, stream>>>(bcmat, xconv_h, pbuf, wbuf, ybuf, sloc);
    chunk_scan_k<<<B_*HEADS_*64, blk, 0, stream>>>(sloc, cdec);
    hipMemsetAsync(gstat, 0, 2*B_*HEADS_*sizeof(float), stream);
    ssd_phase3<<<NCHUNK_, blk, 0, stream>>>(bcmat, xconv_h, sloc, eAb, d_par, ybuf, gstat);
    gn_gate_h<<<(M_*(INNER_/8))/256, blk, 0, stream>>>(ybuf, zbuf_h, gstat, gn_w, gn_b, gbuf_h);
    hgemm<false><<<dim3(DIM_/128, M_/128), blk, 0, stream>>>(gbuf_h, wout_h, out, INNER_, DIM_);
}

// Round 3
// 405.192 us; speedup vs baseline: 3.5190x; 1.0942x over previous
//
#include <hip/hip_runtime.h>
#include <math.h>

// ---------------- problem constants ----------------
#define DIM_   1024
#define STATE_ 64
#define HEADS_ 8
#define INNER_ 2048
#define HDIM_  256          // INNER/HEADS
#define B_     2
#define L_     2048
#define M_     (B_*L_)      // 4096 rows total
#define EPS_   1e-5f
#define Q_     64           // SSD chunk length
#define NC_    (L_/Q_)      // 32 chunks per sequence
#define NCHUNK_ (B_*HEADS_*NC_)  // 512 chunk-blocks
#define BCS_   1024         // combined B|C projection row stride
#define XZS_   4096         // combined x|z row stride

typedef _Float16 f16;
typedef __attribute__((ext_vector_type(8))) _Float16 half8;
typedef __attribute__((ext_vector_type(4))) _Float16 half4;
typedef __attribute__((ext_vector_type(4))) float    f32x4;

__device__ __forceinline__ float siluf(float x) { return x / (1.f + expf(-x)); }

__device__ __forceinline__ void gload_lds16(const void* g, void* l) {
    __builtin_amdgcn_global_load_lds((const __attribute__((address_space(1))) void*)g,
                                     (__attribute__((address_space(3))) void*)l, 16, 0, 0);
}

// ---------------- merged fp32 -> f16 cast of all operands ----------------
// f4-index ranges: input 1048576 | Wx 524288 | Wz 524288 | Wb 262144 | Wc 262144 | Wout 524288
__global__ __launch_bounds__(256) void cast_all(const float* __restrict__ in0,
                                                const float* __restrict__ Wx,
                                                const float* __restrict__ Wz,
                                                const float* __restrict__ Wb,
                                                const float* __restrict__ Wc,
                                                const float* __restrict__ Wout,
                                                f16* __restrict__ input_h,
                                                f16* __restrict__ wxz_h,
                                                f16* __restrict__ wbc_h,
                                                f16* __restrict__ wout_h) {
    int i = blockIdx.x * 256 + threadIdx.x;
    const float* src; f16* dst; int off;
    if      (i < 1048576) { src = in0;  dst = input_h;            off = i; }
    else if (i < 1572864) { src = Wx;   dst = wxz_h;              off = i - 1048576; }
    else if (i < 2097152) { src = Wz;   dst = wxz_h + 2097152;    off = i - 1572864; }
    else if (i < 2359296) { src = Wb;   dst = wbc_h;              off = i - 2097152; }
    else if (i < 2621440) { src = Wc;   dst = wbc_h + 1048576;    off = i - 2359296; }
    else                  { src = Wout; dst = wout_h;             off = i - 2621440; }
    float4 v = *(const float4*)&src[(size_t)off * 4];
    half4 o;
    o[0] = (f16)v.x; o[1] = (f16)v.y; o[2] = (f16)v.z; o[3] = (f16)v.w;
    *(half4*)&dst[(size_t)off * 4] = o;
}

// ---------------- f16 MFMA GEMM: C[M x N] = A[M x K] * W[N x K]^T ----------------
// BM=128, BK=32, templated BN in {64,128}. 4 waves: wr in {0,1} x wc in {0,1},
// per-wave 64 x BN/2 output. global_load_lds(16B) with pre-swizzled source +
// swizzled ds_read_b128: phys slot p = row*4 + (kg ^ ((row>>1)&3)) (involution).
template<int BN, bool OUTF16>
__global__ __launch_bounds__(256) void hgemm(const f16* __restrict__ A,
                                             const f16* __restrict__ W,
                                             void* __restrict__ Cout,
                                             int K, int N) {
    constexpr int N_FR = BN / 32;            // per-wave n fragments
    constexpr int NITER = (128 + BN) / 64;   // staging issues per thread
    __shared__ f16 sA[128 * 32];
    __shared__ f16 sW[BN * 32];
    const int tid  = threadIdx.x;
    const int wid  = tid >> 6;
    const int lane = tid & 63;
    const int bm = blockIdx.y * 128;
    const int bn = blockIdx.x * BN;
    const int wr = wid >> 1, wc = wid & 1;
    const int r  = lane & 15, kg = lane >> 4;

    // staging pointers: slot s = tid + i*256; A slots [0,512), W slots [512, 512+BN*4)
    const f16* gsrc[NITER];
    f16* ldst[NITER];
#pragma unroll
    for (int i = 0; i < NITER; ++i) {
        int slot = tid + i * 256;
        if (slot < 512) {
            int row = slot >> 2;
            int kgv = ((slot & 3) ^ ((row >> 1) & 3)) * 8;
            gsrc[i] = A + (size_t)(bm + row) * K + kgv;
        } else {
            int row = (slot - 512) >> 2;
            int kgv = ((slot & 3) ^ ((row >> 1) & 3)) * 8;
            gsrc[i] = W + (size_t)(bn + row) * K + kgv;
        }
        int slot0 = (tid & ~63) + i * 256;   // wave-uniform base slot
        ldst[i] = (slot0 < 512) ? &sA[slot0 * 8] : &sW[(slot0 - 512) * 8];
    }

    // fragment read offsets (swizzled), k-invariant
    int aoff[4], boff[N_FR];
#pragma unroll
    for (int m = 0; m < 4; ++m) {
        int arow = wr * 64 + m * 16 + r;
        aoff[m] = arow * 32 + ((kg ^ ((arow >> 1) & 3)) << 3);
    }
#pragma unroll
    for (int n = 0; n < N_FR; ++n) {
        int wrow = wc * (BN / 2) + n * 16 + r;
        boff[n] = wrow * 32 + ((kg ^ ((wrow >> 1) & 3)) << 3);
    }

    f32x4 acc[4][N_FR];
#pragma unroll
    for (int m = 0; m < 4; ++m)
#pragma unroll
        for (int n = 0; n < N_FR; ++n) acc[m][n] = (f32x4)0.f;

    for (int k0 = 0; k0 < K; k0 += 32) {
#pragma unroll
        for (int i = 0; i < NITER; ++i) gload_lds16(gsrc[i] + k0, ldst[i]);
        __syncthreads();                 // drains vmcnt: tiles ready
        half8 av[4], bv[N_FR];
#pragma unroll
        for (int m = 0; m < 4; ++m) av[m] = *(const half8*)&sA[aoff[m]];
#pragma unroll
        for (int n = 0; n < N_FR; ++n) bv[n] = *(const half8*)&sW[boff[n]];
#pragma unroll
        for (int m = 0; m < 4; ++m)
#pragma unroll
            for (int n = 0; n < N_FR; ++n)
                acc[m][n] = __builtin_amdgcn_mfma_f32_16x16x32_f16(av[m], bv[n], acc[m][n], 0, 0, 0);
        __syncthreads();                 // all reads done before next overwrite
    }

    // C/D layout: col = lane&15, row = (lane>>4)*4 + j
#pragma unroll
    for (int m = 0; m < 4; ++m)
#pragma unroll
        for (int n = 0; n < N_FR; ++n) {
            int row0o = bm + wr * 64 + m * 16 + kg * 4;
            int col   = bn + wc * (BN / 2) + n * 16 + r;
#pragma unroll
            for (int j = 0; j < 4; ++j) {
                if (OUTF16) ((f16*)Cout)[(size_t)(row0o + j) * N + col] = (f16)acc[m][n][j];
                else        ((float*)Cout)[(size_t)(row0o + j) * N + col] = acc[m][n][j];
            }
        }
}

// ---------------- causal conv (K=4) + bias + SiLU + fused dt-projection ----------------
// One block per row m: 256 threads x 8 channels = 2048 = INNER.
__global__ __launch_bounds__(256) void conv_silu_dt(const f16* __restrict__ xz,
                                                    const float* __restrict__ cw,
                                                    const float* __restrict__ cb,
                                                    const float* __restrict__ Wdt,
                                                    const float* __restrict__ bdt,
                                                    f16* __restrict__ xc,
                                                    float* __restrict__ dtb) {
    __shared__ float sred[4][HEADS_];
    const int m = blockIdx.x;
    const int tid = threadIdx.x;
    const int c8 = tid * 8;
    const int t = m & (L_ - 1);
    float acc[8];
    float4 wv[8];
#pragma unroll
    for (int j = 0; j < 8; ++j) { acc[j] = cb[c8 + j]; wv[j] = *(const float4*)&cw[(c8 + j) * 4]; }
#pragma unroll
    for (int k = 0; k < 4; ++k) {
        int tt = t - 3 + k;
        if (tt >= 0) {
            half8 xv = *(const half8*)&xz[(size_t)(m - 3 + k) * XZS_ + c8];
#pragma unroll
            for (int j = 0; j < 8; ++j) acc[j] += (float)xv[j] * ((const float*)&wv[j])[k];
        }
    }
    float xf[8];
    half8 o;
#pragma unroll
    for (int j = 0; j < 8; ++j) { xf[j] = siluf(acc[j]); o[j] = (f16)xf[j]; }
    *(half8*)&xc[(size_t)m * INNER_ + c8] = o;

    // dt partials: every thread contributes to all 8 heads
    float p[HEADS_];
#pragma unroll
    for (int h = 0; h < HEADS_; ++h) {
        float4 w0 = *(const float4*)&Wdt[h * INNER_ + c8];
        float4 w1 = *(const float4*)&Wdt[h * INNER_ + c8 + 4];
        p[h] = xf[0]*w0.x + xf[1]*w0.y + xf[2]*w0.z + xf[3]*w0.w
             + xf[4]*w1.x + xf[5]*w1.y + xf[6]*w1.z + xf[7]*w1.w;
    }
#pragma unroll
    for (int h = 0; h < HEADS_; ++h)
#pragma unroll
        for (int off = 32; off > 0; off >>= 1)
            p[h] += __shfl_down(p[h], off, 64);
    if ((tid & 63) == 0) {
#pragma unroll
        for (int h = 0; h < HEADS_; ++h) sred[tid >> 6][h] = p[h];
    }
    __syncthreads();
    if (tid < 32) {
        float v = sred[tid >> 3][tid & 7];
        v += __shfl_down(v, 16, 32);
        v += __shfl_down(v, 8, 32);
        if (tid < 8) {
            float s = v + bdt[tid];
            dtb[(size_t)m * HEADS_ + tid] = (s > 20.f) ? s : log1pf(expf(s));
        }
    }
}

// ---------------- SSD phase 1: per-chunk cumdecay + P = mask(C·B^T)·scale ----------------
__global__ __launch_bounds__(256) void ssd_phase1(const float* __restrict__ bc,
                                                  const float* __restrict__ dtb,
                                                  const float* __restrict__ log_a,
                                                  float* __restrict__ pbuf,
                                                  float* __restrict__ eAbuf,
                                                  float* __restrict__ wbuf,
                                                  float* __restrict__ cdecay) {
    __shared__ float sBt[STATE_][Q_+1];   // [n][s]
    __shared__ float sCt[STATE_][Q_+1];   // [n][t]
    __shared__ float sA[Q_];
    __shared__ float sDt[Q_];
    const int tid = threadIdx.x;
    const int chunk = blockIdx.x;
    const int bh = chunk / NC_;
    const int ck = chunk - bh * NC_;
    const int b = bh >> 3, h = bh & 7;
    const int m0 = b * L_ + ck * Q_;

    if (tid < 64) {                // wave 0: inclusive prefix scan of dt*a
        float dt = dtb[(size_t)(m0 + tid) * HEADS_ + h];
        float a = -expf(log_a[h]);
        float x = dt * a;
#pragma unroll
        for (int off = 1; off < 64; off <<= 1) {
            float v = __shfl_up(x, off, 64);
            if (tid >= off) x += v;
        }
        float Alast = __shfl(x, 63, 64);
        sA[tid] = x;
        sDt[tid] = dt;
        eAbuf[(size_t)(m0 + tid) * HEADS_ + h] = expf(x);
        wbuf[(size_t)chunk * Q_ + tid] = expf(Alast - x) * dt;
        if (tid == 0) cdecay[chunk] = expf(Alast);
    }
#pragma unroll
    for (int l = 0; l < 4; ++l) {     // stage B,C transposed (k-major)
        int q = tid + l * 256;
        int s = q >> 4;
        int n0 = (q & 15) * 4;
        float4 bv = *(const float4*)&bc[(size_t)(m0+s)*BCS_ + h*STATE_ + n0];
        float4 cv = *(const float4*)&bc[(size_t)(m0+s)*BCS_ + 512 + h*STATE_ + n0];
        sBt[n0+0][s] = bv.x; sBt[n0+1][s] = bv.y; sBt[n0+2][s] = bv.z; sBt[n0+3][s] = bv.w;
        sCt[n0+0][s] = cv.x; sCt[n0+1][s] = cv.y; sCt[n0+2][s] = cv.z; sCt[n0+3][s] = cv.w;
    }
    __syncthreads();
    const int tx = tid & 15, ty = tid >> 4;
    float g[4][4];
#pragma unroll
    for (int i = 0; i < 4; ++i)
#pragma unroll
        for (int j = 0; j < 4; ++j) g[i][j] = 0.f;
    for (int n = 0; n < STATE_; ++n) {
        float cv[4], bv[4];
#pragma unroll
        for (int i = 0; i < 4; ++i) cv[i] = sCt[n][ty*4+i];
#pragma unroll
        for (int j = 0; j < 4; ++j) bv[j] = sBt[n][tx*4+j];
#pragma unroll
        for (int i = 0; i < 4; ++i)
#pragma unroll
            for (int j = 0; j < 4; ++j) g[i][j] += cv[i] * bv[j];
    }
#pragma unroll
    for (int i = 0; i < 4; ++i) {
        int t = ty*4 + i;
        float At = sA[t];
        float o[4];
#pragma unroll
        for (int j = 0; j < 4; ++j) {
            int s = tx*4 + j;
            o[j] = (t >= s) ? g[i][j] * expf(At - sA[s]) * sDt[s] : 0.f;
        }
        *(float4*)&pbuf[((size_t)chunk * Q_ + t) * Q_ + tx*4] = make_float4(o[0],o[1],o[2],o[3]);
    }
}

// ---------------- SSD phase 2: Y_intra = P·X ; S_local = (w·B)^T·X ----------------
__global__ __launch_bounds__(256) void ssd_phase2(const float* __restrict__ bc,
                                                  const f16* __restrict__ xch,
                                                  const float* __restrict__ pbuf,
                                                  const float* __restrict__ wbuf,
                                                  float* __restrict__ ybuf,
                                                  float* __restrict__ sloc) {
    __shared__ float sPt[Q_][Q_+1];       // [s][t]
    __shared__ float sBw[Q_][STATE_+1];   // [s][n] (scaled)
    __shared__ float sX[Q_][Q_+4];        // [s][p-tile]
    const int tid = threadIdx.x;
    const int chunk = blockIdx.x;
    const int bh = chunk / NC_;
    const int ck = chunk - bh * NC_;
    const int b = bh >> 3, h = bh & 7;
    const int m0 = b * L_ + ck * Q_;

#pragma unroll
    for (int l = 0; l < 4; ++l) {
        int q = tid + l * 256;
        int t = q >> 4;
        int s0 = (q & 15) * 4;
        float4 pv = *(const float4*)&pbuf[((size_t)chunk*Q_ + t)*Q_ + s0];
        sPt[s0+0][t] = pv.x; sPt[s0+1][t] = pv.y; sPt[s0+2][t] = pv.z; sPt[s0+3][t] = pv.w;
        int s = t;            // same decomposition for B staging
        int n0 = s0;
        float ws = wbuf[(size_t)chunk * Q_ + s];
        float4 bv = *(const float4*)&bc[(size_t)(m0+s)*BCS_ + h*STATE_ + n0];
        sBw[s][n0+0] = bv.x * ws; sBw[s][n0+1] = bv.y * ws;
        sBw[s][n0+2] = bv.z * ws; sBw[s][n0+3] = bv.w * ws;
    }
    const int tx = tid & 15, ty = tid >> 4;
    for (int pt = 0; pt < 4; ++pt) {
        int p0 = pt * 64;
        __syncthreads();
#pragma unroll
        for (int l = 0; l < 2; ++l) {
            int q = tid + l * 256;       // 0..511
            int s = q >> 3;              // 0..63
            int pp = (q & 7) * 8;
            half8 xv = *(const half8*)&xch[(size_t)(m0+s)*INNER_ + h*HDIM_ + p0 + pp];
#pragma unroll
            for (int j = 0; j < 8; ++j) sX[s][pp+j] = (float)xv[j];
        }
        __syncthreads();
        float accY[4][4], accS[4][4];
#pragma unroll
        for (int i = 0; i < 4; ++i)
#pragma unroll
            for (int j = 0; j < 4; ++j) { accY[i][j] = 0.f; accS[i][j] = 0.f; }
        for (int s = 0; s < Q_; ++s) {
            float pv[4], bv[4];
#pragma unroll
            for (int i = 0; i < 4; ++i) { pv[i] = sPt[s][ty*4+i]; bv[i] = sBw[s][ty*4+i]; }
            float4 xv = *(const float4*)&sX[s][tx*4];
            float xq[4] = {xv.x, xv.y, xv.z, xv.w};
#pragma unroll
            for (int i = 0; i < 4; ++i)
#pragma unroll
                for (int j = 0; j < 4; ++j) {
                    accY[i][j] += pv[i] * xq[j];
                    accS[i][j] += bv[i] * xq[j];
                }
        }
#pragma unroll
        for (int i = 0; i < 4; ++i) {
            int t = ty*4 + i;       // also the n index for S_local
            *(float4*)&ybuf[(size_t)(m0+t)*INNER_ + h*HDIM_ + p0 + tx*4] =
                make_float4(accY[i][0], accY[i][1], accY[i][2], accY[i][3]);
            *(float4*)&sloc[((size_t)chunk*STATE_ + t)*HDIM_ + p0 + tx*4] =
                make_float4(accS[i][0], accS[i][1], accS[i][2], accS[i][3]);
        }
    }
}

// ---------------- SSD phase B: sequential inter-chunk state recurrence ----------------
__global__ __launch_bounds__(256) void chunk_scan_k(float* __restrict__ sloc,
                                                    const float* __restrict__ cdecay) {
    int bh = blockIdx.x >> 6;
    int el = (blockIdx.x & 63) * 256 + threadIdx.x;  // 0..16383 within (n,p)
    float s = 0.f;
    for (int c = 0; c < NC_; ++c) {
        size_t chunk = (size_t)bh * NC_ + c;
        float* ptr = sloc + chunk * (size_t)(STATE_*HDIM_) + el;
        float tmp = *ptr;
        *ptr = s;                    // becomes S_in for this chunk
        s = cdecay[chunk] * s + tmp;
    }
}

// ---------------- SSD phase 3: y += exp(A_t)·(C·S_in) + d·x ; GN partial sums ----------------
__global__ __launch_bounds__(256) void ssd_phase3(const float* __restrict__ bc,
                                                  const f16* __restrict__ xch,
                                                  const float* __restrict__ sloc,
                                                  const float* __restrict__ eAbuf,
                                                  const float* __restrict__ dparam,
                                                  float* __restrict__ ybuf,
                                                  float* __restrict__ gstats) {
    __shared__ float sCt[STATE_][Q_+1];   // [n][t]
    __shared__ float sS[STATE_][Q_+4];    // [n][p-tile]
    __shared__ float red[512];
    const int tid = threadIdx.x;
    const int chunk = blockIdx.x;
    const int bh = chunk / NC_;
    const int ck = chunk - bh * NC_;
    const int b = bh >> 3, h = bh & 7;
    const int m0 = b * L_ + ck * Q_;

#pragma unroll
    for (int l = 0; l < 4; ++l) {
        int q = tid + l * 256;
        int t = q >> 4;
        int n0 = (q & 15) * 4;
        float4 cv = *(const float4*)&bc[(size_t)(m0+t)*BCS_ + 512 + h*STATE_ + n0];
        sCt[n0+0][t] = cv.x; sCt[n0+1][t] = cv.y; sCt[n0+2][t] = cv.z; sCt[n0+3][t] = cv.w;
    }
    const int tx = tid & 15, ty = tid >> 4;
    const float d = dparam[h];
    float lsum = 0.f, lsq = 0.f;
    for (int pt = 0; pt < 4; ++pt) {
        int p0 = pt * 64;
        __syncthreads();
#pragma unroll
        for (int l = 0; l < 4; ++l) {
            int q = tid + l * 256;
            int n = q >> 4;
            int pp = (q & 15) * 4;
            *(float4*)&sS[n][pp] = *(const float4*)&sloc[((size_t)chunk*STATE_ + n)*HDIM_ + p0 + pp];
        }
        __syncthreads();
        float acc[4][4];
#pragma unroll
        for (int i = 0; i < 4; ++i)
#pragma unroll
            for (int j = 0; j < 4; ++j) acc[i][j] = 0.f;
        for (int n = 0; n < STATE_; ++n) {
            float cv[4];
#pragma unroll
            for (int i = 0; i < 4; ++i) cv[i] = sCt[n][ty*4+i];
            float4 sv = *(const float4*)&sS[n][tx*4];
            float sq[4] = {sv.x, sv.y, sv.z, sv.w};
#pragma unroll
            for (int i = 0; i < 4; ++i)
#pragma unroll
                for (int j = 0; j < 4; ++j) acc[i][j] += cv[i] * sq[j];
        }
#pragma unroll
        for (int i = 0; i < 4; ++i) {
            int t = ty*4 + i;
            float eA = eAbuf[(size_t)(m0+t)*HEADS_ + h];
            size_t off = (size_t)(m0+t)*INNER_ + h*HDIM_ + p0 + tx*4;
            float4 yin = *(const float4*)&ybuf[off];
            half4 xv4 = *(const half4*)&xch[off];
            float4 o;
            o.x = yin.x + eA*acc[i][0] + d*(float)xv4[0];
            o.y = yin.y + eA*acc[i][1] + d*(float)xv4[1];
            o.z = yin.z + eA*acc[i][2] + d*(float)xv4[2];
            o.w = yin.w + eA*acc[i][3] + d*(float)xv4[3];
            *(float4*)&ybuf[off] = o;
            lsum += o.x + o.y + o.z + o.w;
            lsq  += o.x*o.x + o.y*o.y + o.z*o.z + o.w*o.w;
        }
    }
    __syncthreads();
    red[tid] = lsum; red[256+tid] = lsq;
    __syncthreads();
    for (int st = 128; st > 0; st >>= 1) {
        if (tid < st) { red[tid] += red[tid+st]; red[256+tid] += red[256+tid+st]; }
        __syncthreads();
    }
    if (tid == 0) {
        atomicAdd(&gstats[bh*2+0], red[0]);
        atomicAdd(&gstats[bh*2+1], red[256]);
    }
}

// ---------------- GroupNorm finalize + gate: g = (norm(y)*w+b) * silu(z) ----------------
__global__ __launch_bounds__(256) void gn_gate_h(const float* __restrict__ ybuf,
                                                 const f16* __restrict__ xz,
                                                 const float* __restrict__ gstats,
                                                 const float* __restrict__ gnw,
                                                 const float* __restrict__ gnb,
                                                 f16* __restrict__ g) {
    int idx = blockIdx.x * 256 + threadIdx.x;    // over M_*INNER_/8
    int c8 = (idx & (INNER_/8 - 1)) * 8;
    int m = idx >> 8;
    int bh = (m >> 11) * HEADS_ + (c8 >> 8);
    const float cnt = (float)(L_ * HDIM_);
    float mean = gstats[bh*2] / cnt;
    float var  = gstats[bh*2+1] / cnt - mean*mean;
    float rstd = rsqrtf(var + EPS_);
    size_t off = (size_t)m * INNER_ + c8;
    float4 y0 = *(const float4*)&ybuf[off];
    float4 y1 = *(const float4*)&ybuf[off + 4];
    half8 zv = *(const half8*)&xz[(size_t)m * XZS_ + INNER_ + c8];
    float4 w0 = *(const float4*)&gnw[c8], w1 = *(const float4*)&gnw[c8+4];
    float4 b0 = *(const float4*)&gnb[c8], b1 = *(const float4*)&gnb[c8+4];
    float yn[8] = {y0.x, y0.y, y0.z, y0.w, y1.x, y1.y, y1.z, y1.w};
    float wv[8] = {w0.x, w0.y, w0.z, w0.w, w1.x, w1.y, w1.z, w1.w};
    float bv[8] = {b0.x, b0.y, b0.z, b0.w, b1.x, b1.y, b1.z, b1.w};
    half8 o;
#pragma unroll
    for (int j = 0; j < 8; ++j) {
        float v = (yn[j] - mean) * rstd * wv[j] + bv[j];
        o[j] = (f16)(v * siluf((float)zv[j]));
    }
    *(half8*)&g[off] = o;
}

// ---------------- launch ----------------
extern "C" void kernel_launch(void* const* d_in, const int* in_sizes, int n_in,
                              void* d_out, int out_size, void* d_ws, size_t ws_size,
                              hipStream_t stream) {
    const float* input  = (const float*)d_in[0];
    const float* Wx     = (const float*)d_in[1];
    const float* Wz     = (const float*)d_in[2];
    const float* conv_w = (const float*)d_in[3];
    const float* conv_b = (const float*)d_in[4];
    const float* Wb     = (const float*)d_in[5];
    const float* Wc     = (const float*)d_in[6];
    const float* Wdt    = (const float*)d_in[7];
    const float* b_dt   = (const float*)d_in[8];
    const float* log_a  = (const float*)d_in[9];
    const float* d_par  = (const float*)d_in[10];
    const float* gn_w   = (const float*)d_in[11];
    const float* gn_b   = (const float*)d_in[12];
    const float* Wout   = (const float*)d_in[13];
    float* out = (float*)d_out;

    float* ws = (float*)d_ws;
    size_t off = 0;
    auto alloc = [&](size_t nfloats) { float* p = ws + off; off += (nfloats + 63) & ~(size_t)63; return p; };
    f16* input_h = (f16*)alloc((size_t)M_*DIM_/2);
    f16* wxz_h   = (f16*)alloc((size_t)XZS_*DIM_/2);
    f16* wbc_h   = (f16*)alloc((size_t)BCS_*INNER_/2);
    f16* wout_h  = (f16*)alloc((size_t)DIM_*INNER_/2);
    f16* xz_h    = (f16*)alloc((size_t)M_*XZS_/2);
    f16* xconv_h = (f16*)alloc((size_t)M_*INNER_/2);
    f16* gbuf_h  = (f16*)alloc((size_t)M_*INNER_/2);
    float* bcmat = alloc((size_t)M_*BCS_);
    float* dtb   = alloc((size_t)M_*HEADS_);
    float* eAb   = alloc((size_t)M_*HEADS_);
    float* wbuf  = alloc((size_t)NCHUNK_*Q_);
    float* ybuf  = alloc((size_t)M_*INNER_);
    float* pbuf  = alloc((size_t)NCHUNK_*Q_*Q_);
    float* sloc  = alloc((size_t)NCHUNK_*STATE_*HDIM_);
    float* cdec  = alloc((size_t)NCHUNK_);
    float* gstat = alloc((size_t)2*B_*HEADS_);

    dim3 blk(256);

    cast_all<<<12288, blk, 0, stream>>>(input, Wx, Wz, Wb, Wc, Wout,
                                        input_h, wxz_h, wbc_h, wout_h);
    hgemm<128,true><<<dim3(XZS_/128, M_/128), blk, 0, stream>>>(input_h, wxz_h, xz_h, DIM_, XZS_);
    conv_silu_dt<<<M_, blk, 0, stream>>>(xz_h, conv_w, conv_b, Wdt, b_dt, xconv_h, dtb);
    hgemm<64,false><<<dim3(BCS_/64, M_/128), blk, 0, stream>>>(xconv_h, wbc_h, bcmat, INNER_, BCS_);
    ssd_phase1<<<NCHUNK_, blk, 0, stream>>>(bcmat, dtb, log_a, pbuf, eAb, wbuf, cdec);
    ssd_phase2<<<NCHUNK_, blk, 0, stream>>>(bcmat, xconv_h, pbuf, wbuf, ybuf, sloc);
    chunk_scan_k<<<B_*HEADS_*64, blk, 0, stream>>>(sloc, cdec);
    hipMemsetAsync(gstat, 0, 2*B_*HEADS_*sizeof(float), stream);
    ssd_phase3<<<NCHUNK_, blk, 0, stream>>>(bcmat, xconv_h, sloc, eAb, d_par, ybuf, gstat);
    gn_gate_h<<<(M_*(INNER_/8))/256, blk, 0, stream>>>(ybuf, xz_h, gstat, gn_w, gn_b, gbuf_h);
    hgemm<64,false><<<dim3(DIM_/64, M_/128), blk, 0, stream>>>(gbuf_h, wout_h, out, INNER_, DIM_);
}

// Round 6
// 363.254 us; speedup vs baseline: 3.9253x; 1.1155x over previous
//
#include <hip/hip_runtime.h>
#include <math.h>

// ---------------- problem constants ----------------
#define DIM_   1024
#define STATE_ 64
#define HEADS_ 8
#define INNER_ 2048
#define HDIM_  256          // INNER/HEADS
#define B_     2
#define L_     2048
#define M_     (B_*L_)      // 4096 rows total
#define EPS_   1e-5f
#define Q_     64           // SSD chunk length
#define NC_    (L_/Q_)      // 32 chunks per sequence
#define NCHUNK_ (B_*HEADS_*NC_)  // 512 chunk-blocks
#define BCS_   1024         // combined B|C projection row stride
#define XZS_   4096         // combined x|z row stride

typedef _Float16 f16;
typedef __attribute__((ext_vector_type(8))) _Float16 half8;
typedef __attribute__((ext_vector_type(4))) _Float16 half4;
typedef __attribute__((ext_vector_type(4))) float    f32x4;

__device__ __forceinline__ float siluf(float x) { return x / (1.f + expf(-x)); }

__device__ __forceinline__ void gload_lds16(const void* g, void* l) {
    __builtin_amdgcn_global_load_lds((const __attribute__((address_space(1))) void*)g,
                                     (__attribute__((address_space(3))) void*)l, 16, 0, 0);
}

// ---------------- merged fp32 -> f16 cast of all operands ----------------
__global__ __launch_bounds__(256) void cast_all(const float* __restrict__ in0,
                                                const float* __restrict__ Wx,
                                                const float* __restrict__ Wz,
                                                const float* __restrict__ Wb,
                                                const float* __restrict__ Wc,
                                                const float* __restrict__ Wout,
                                                f16* __restrict__ input_h,
                                                f16* __restrict__ wxz_h,
                                                f16* __restrict__ wbc_h,
                                                f16* __restrict__ wout_h) {
    int i = blockIdx.x * 256 + threadIdx.x;
    const float* src; f16* dst; int off;
    if      (i < 1048576) { src = in0;  dst = input_h;            off = i; }
    else if (i < 1572864) { src = Wx;   dst = wxz_h;              off = i - 1048576; }
    else if (i < 2097152) { src = Wz;   dst = wxz_h + 2097152;    off = i - 1572864; }
    else if (i < 2359296) { src = Wb;   dst = wbc_h;              off = i - 2097152; }
    else if (i < 2621440) { src = Wc;   dst = wbc_h + 1048576;    off = i - 2359296; }
    else                  { src = Wout; dst = wout_h;             off = i - 2621440; }
    float4 v = *(const float4*)&src[(size_t)off * 4];
    half4 o;
    o[0] = (f16)v.x; o[1] = (f16)v.y; o[2] = (f16)v.z; o[3] = (f16)v.w;
    *(half4*)&dst[(size_t)off * 4] = o;
}

// ---------------- f16 MFMA GEMM: C[M x N] = A[M x K] * W[N x K]^T ----------------
template<int BN, bool OUTF16>
__global__ __launch_bounds__(256) void hgemm(const f16* __restrict__ A,
                                             const f16* __restrict__ W,
                                             void* __restrict__ Cout,
                                             int K, int N) {
    constexpr int N_FR = BN / 32;            // per-wave n fragments
    constexpr int NITER = (128 + BN) / 64;   // staging issues per thread
    __shared__ f16 sA[128 * 32];
    __shared__ f16 sW[BN * 32];
    const int tid  = threadIdx.x;
    const int wid  = tid >> 6;
    const int lane = tid & 63;
    const int bm = blockIdx.y * 128;
    const int bn = blockIdx.x * BN;
    const int wr = wid >> 1, wc = wid & 1;
    const int r  = lane & 15, kg = lane >> 4;

    const f16* gsrc[NITER];
    f16* ldst[NITER];
#pragma unroll
    for (int i = 0; i < NITER; ++i) {
        int slot = tid + i * 256;
        if (slot < 512) {
            int row = slot >> 2;
            int kgv = ((slot & 3) ^ ((row >> 1) & 3)) * 8;
            gsrc[i] = A + (size_t)(bm + row) * K + kgv;
        } else {
            int row = (slot - 512) >> 2;
            int kgv = ((slot & 3) ^ ((row >> 1) & 3)) * 8;
            gsrc[i] = W + (size_t)(bn + row) * K + kgv;
        }
        int slot0 = (tid & ~63) + i * 256;   // wave-uniform base slot
        ldst[i] = (slot0 < 512) ? &sA[slot0 * 8] : &sW[(slot0 - 512) * 8];
    }

    int aoff[4], boff[N_FR];
#pragma unroll
    for (int m = 0; m < 4; ++m) {
        int arow = wr * 64 + m * 16 + r;
        aoff[m] = arow * 32 + ((kg ^ ((arow >> 1) & 3)) << 3);
    }
#pragma unroll
    for (int n = 0; n < N_FR; ++n) {
        int wrow = wc * (BN / 2) + n * 16 + r;
        boff[n] = wrow * 32 + ((kg ^ ((wrow >> 1) & 3)) << 3);
    }

    f32x4 acc[4][N_FR];
#pragma unroll
    for (int m = 0; m < 4; ++m)
#pragma unroll
        for (int n = 0; n < N_FR; ++n) acc[m][n] = (f32x4)0.f;

    for (int k0 = 0; k0 < K; k0 += 32) {
#pragma unroll
        for (int i = 0; i < NITER; ++i) gload_lds16(gsrc[i] + k0, ldst[i]);
        __syncthreads();
        half8 av[4], bv[N_FR];
#pragma unroll
        for (int m = 0; m < 4; ++m) av[m] = *(const half8*)&sA[aoff[m]];
#pragma unroll
        for (int n = 0; n < N_FR; ++n) bv[n] = *(const half8*)&sW[boff[n]];
#pragma unroll
        for (int m = 0; m < 4; ++m)
#pragma unroll
            for (int n = 0; n < N_FR; ++n)
                acc[m][n] = __builtin_amdgcn_mfma_f32_16x16x32_f16(av[m], bv[n], acc[m][n], 0, 0, 0);
        __syncthreads();
    }

#pragma unroll
    for (int m = 0; m < 4; ++m)
#pragma unroll
        for (int n = 0; n < N_FR; ++n) {
            int row0o = bm + wr * 64 + m * 16 + kg * 4;
            int col   = bn + wc * (BN / 2) + n * 16 + r;
#pragma unroll
            for (int j = 0; j < 4; ++j) {
                if (OUTF16) ((f16*)Cout)[(size_t)(row0o + j) * N + col] = (f16)acc[m][n][j];
                else        ((float*)Cout)[(size_t)(row0o + j) * N + col] = acc[m][n][j];
            }
        }
}

// ---------------- causal conv (K=4) + bias + SiLU + fused dt-projection ----------------
__global__ __launch_bounds__(256) void conv_silu_dt(const f16* __restrict__ xz,
                                                    const float* __restrict__ cw,
                                                    const float* __restrict__ cb,
                                                    const float* __restrict__ Wdt,
                                                    const float* __restrict__ bdt,
                                                    f16* __restrict__ xc,
                                                    float* __restrict__ dtb) {
    __shared__ float sred[4][HEADS_];
    const int m = blockIdx.x;
    const int tid = threadIdx.x;
    const int c8 = tid * 8;
    const int t = m & (L_ - 1);
    float acc[8];
    float4 wv[8];
#pragma unroll
    for (int j = 0; j < 8; ++j) { acc[j] = cb[c8 + j]; wv[j] = *(const float4*)&cw[(c8 + j) * 4]; }
#pragma unroll
    for (int k = 0; k < 4; ++k) {
        int tt = t - 3 + k;
        if (tt >= 0) {
            half8 xv = *(const half8*)&xz[(size_t)(m - 3 + k) * XZS_ + c8];
#pragma unroll
            for (int j = 0; j < 8; ++j) acc[j] += (float)xv[j] * ((const float*)&wv[j])[k];
        }
    }
    float xf[8];
    half8 o;
#pragma unroll
    for (int j = 0; j < 8; ++j) { xf[j] = siluf(acc[j]); o[j] = (f16)xf[j]; }
    *(half8*)&xc[(size_t)m * INNER_ + c8] = o;

    float p[HEADS_];
#pragma unroll
    for (int h = 0; h < HEADS_; ++h) {
        float4 w0 = *(const float4*)&Wdt[h * INNER_ + c8];
        float4 w1 = *(const float4*)&Wdt[h * INNER_ + c8 + 4];
        p[h] = xf[0]*w0.x + xf[1]*w0.y + xf[2]*w0.z + xf[3]*w0.w
             + xf[4]*w1.x + xf[5]*w1.y + xf[6]*w1.z + xf[7]*w1.w;
    }
#pragma unroll
    for (int h = 0; h < HEADS_; ++h)
#pragma unroll
        for (int off = 32; off > 0; off >>= 1)
            p[h] += __shfl_down(p[h], off, 64);
    if ((tid & 63) == 0) {
#pragma unroll
        for (int h = 0; h < HEADS_; ++h) sred[tid >> 6][h] = p[h];
    }
    __syncthreads();
    if (tid < 32) {
        float v = sred[tid >> 3][tid & 7];
        v += __shfl_down(v, 16, 32);
        v += __shfl_down(v, 8, 32);
        if (tid < 8) {
            float s = v + bdt[tid];
            dtb[(size_t)m * HEADS_ + tid] = (s > 20.f) ? s : log1pf(expf(s));
        }
    }
}

// ---------------- per-head transpose: xT[bh][p][t] = xconv[b*L+t][h*256+p] ----------------
__global__ __launch_bounds__(256) void xpose_k(const f16* __restrict__ xc,
                                               f16* __restrict__ xT) {
    __shared__ f16 sT[64][72];
    const int blk = blockIdx.x;
    const int bh = blk >> 7;            // 16
    const int rem = blk & 127;
    const int tt = rem >> 2;            // 32 t-tiles
    const int pt = rem & 3;             // 4 p-tiles
    const int b = bh >> 3, h = bh & 7;
    const int tid = threadIdx.x;
#pragma unroll
    for (int it = 0; it < 2; ++it) {
        int q = tid + it * 256;
        int tr = q >> 3;
        int p0 = (q & 7) * 8;
        half8 v = *(const half8*)&xc[(size_t)(b * L_ + tt * 64 + tr) * INNER_ + h * HDIM_ + pt * 64 + p0];
        *(half8*)&sT[tr][p0] = v;
    }
    __syncthreads();
#pragma unroll
    for (int it = 0; it < 2; ++it) {
        int q = tid + it * 256;
        int pr = q >> 3;
        int t0 = (q & 7) * 8;
        half8 v;
#pragma unroll
        for (int j = 0; j < 8; ++j) v[j] = sT[t0 + j][pr];
        *(half8*)&xT[((size_t)bh * HDIM_ + pt * 64 + pr) * L_ + tt * 64 + t0] = v;
    }
}

// ---------------- SSD phase 1: prefix scan + G = C.B^T (MFMA) -> P f16 ----------------
__global__ __launch_bounds__(256) void ssd_phase1(const f16* __restrict__ bc,
                                                  const float* __restrict__ dtb,
                                                  const float* __restrict__ log_a,
                                                  f16* __restrict__ pbuf,
                                                  float* __restrict__ eAbuf,
                                                  float* __restrict__ wbuf,
                                                  float* __restrict__ cdecay) {
    __shared__ float sA[Q_];
    __shared__ float sDt[Q_];
    const int tid = threadIdx.x;
    const int chunk = blockIdx.x;
    const int bh = chunk / NC_;
    const int ck = chunk - bh * NC_;
    const int b = bh >> 3, h = bh & 7;
    const int m0 = b * L_ + ck * Q_;

    if (tid < 64) {                // wave 0: inclusive prefix scan of dt*a
        float dt = dtb[(size_t)(m0 + tid) * HEADS_ + h];
        float a = -expf(log_a[h]);
        float x = dt * a;
#pragma unroll
        for (int off = 1; off < 64; off <<= 1) {
            float v = __shfl_up(x, off, 64);
            if (tid >= off) x += v;
        }
        float Alast = __shfl(x, 63, 64);
        sA[tid] = x;
        sDt[tid] = dt;
        eAbuf[(size_t)(m0 + tid) * HEADS_ + h] = expf(x);
        wbuf[(size_t)chunk * Q_ + tid] = expf(Alast - x) * dt;
        if (tid == 0) cdecay[chunk] = expf(Alast);
    }
    __syncthreads();

    const int w = tid >> 6, lane = tid & 63;
    const int r = lane & 15, kg = lane >> 4;
    const int ft = w;                       // t-fragment of this wave
    const f16* Crow = bc + (size_t)(m0 + ft * 16 + r) * BCS_ + 512 + h * STATE_;
    half8 a0 = *(const half8*)(Crow + kg * 8);
    half8 a1 = *(const half8*)(Crow + 32 + kg * 8);
#pragma unroll
    for (int fs = 0; fs < 4; ++fs) {
        const f16* Brow = bc + (size_t)(m0 + fs * 16 + r) * BCS_ + h * STATE_;
        half8 b0 = *(const half8*)(Brow + kg * 8);
        half8 b1 = *(const half8*)(Brow + 32 + kg * 8);
        f32x4 g = (f32x4)0.f;
        g = __builtin_amdgcn_mfma_f32_16x16x32_f16(a0, b0, g, 0, 0, 0);
        g = __builtin_amdgcn_mfma_f32_16x16x32_f16(a1, b1, g, 0, 0, 0);
        int s = fs * 16 + r;
        float As = sA[s], dts = sDt[s];
#pragma unroll
        for (int j = 0; j < 4; ++j) {
            int t = ft * 16 + kg * 4 + j;
            float val = (t >= s) ? g[j] * expf(sA[t] - As) * dts : 0.f;
            pbuf[((size_t)chunk * Q_ + t) * Q_ + s] = (f16)val;
        }
    }
}

// ---------------- w-scaled B transpose: bwT[chunk][n][s] = B[m0+s][h*64+n]*w[s] ----------------
__global__ __launch_bounds__(256) void bwt_k(const f16* __restrict__ bc,
                                             const float* __restrict__ wbuf,
                                             f16* __restrict__ bwT) {
    __shared__ f16 sT[64][72];
    __shared__ float sw[64];
    const int chunk = blockIdx.x;
    const int bh = chunk / NC_;
    const int ck = chunk - bh * NC_;
    const int b = bh >> 3, h = bh & 7;
    const int m0 = b * L_ + ck * Q_;
    const int tid = threadIdx.x;
    if (tid < 64) sw[tid] = wbuf[(size_t)chunk * Q_ + tid];
#pragma unroll
    for (int it = 0; it < 2; ++it) {
        int q = tid + it * 256;
        int s = q >> 3;
        int n0 = (q & 7) * 8;
        half8 v = *(const half8*)&bc[(size_t)(m0 + s) * BCS_ + h * STATE_ + n0];
        *(half8*)&sT[s][n0] = v;
    }
    __syncthreads();
#pragma unroll
    for (int it = 0; it < 2; ++it) {
        int q = tid + it * 256;
        int n = q >> 3;
        int s0 = (q & 7) * 8;
        half8 o;
#pragma unroll
        for (int j = 0; j < 8; ++j) o[j] = (f16)((float)sT[s0 + j][n] * sw[s0 + j]);
        *(half8*)&bwT[((size_t)chunk * Q_ + n) * Q_ + s0] = o;
    }
}

// ---------------- SSD phase 2 (MFMA): S^T[p][n] = sum_s X^T[p][s] * Bw^T[n][s] ----------------
__global__ __launch_bounds__(256) void ssd_phase2(const f16* __restrict__ xT,
                                                  const f16* __restrict__ bwT,
                                                  f16* __restrict__ sloc) {
    const int tid = threadIdx.x;
    const int chunk = blockIdx.x;
    const int bh = chunk / NC_;
    const int ck = chunk - bh * NC_;
    const int w = tid >> 6, lane = tid & 63;
    const int r = lane & 15, kg = lane >> 4;

    f32x4 acc[4][4];
#pragma unroll
    for (int i = 0; i < 4; ++i)
#pragma unroll
        for (int j = 0; j < 4; ++j) acc[i][j] = (f32x4)0.f;

#pragma unroll
    for (int kk = 0; kk < 2; ++kk) {
        half8 a[4], bfr[4];
#pragma unroll
        for (int pf = 0; pf < 4; ++pf) {
            int p = w * 64 + pf * 16 + r;
            a[pf] = *(const half8*)&xT[((size_t)bh * HDIM_ + p) * L_ + ck * Q_ + kk * 32 + kg * 8];
        }
#pragma unroll
        for (int nf = 0; nf < 4; ++nf) {
            int n = nf * 16 + r;
            bfr[nf] = *(const half8*)&bwT[((size_t)chunk * Q_ + n) * Q_ + kk * 32 + kg * 8];
        }
#pragma unroll
        for (int pf = 0; pf < 4; ++pf)
#pragma unroll
            for (int nf = 0; nf < 4; ++nf)
                acc[pf][nf] = __builtin_amdgcn_mfma_f32_16x16x32_f16(a[pf], bfr[nf], acc[pf][nf], 0, 0, 0);
    }
#pragma unroll
    for (int pf = 0; pf < 4; ++pf)
#pragma unroll
        for (int nf = 0; nf < 4; ++nf) {
            int n = nf * 16 + r;
#pragma unroll
            for (int j = 0; j < 4; ++j) {
                int p = w * 64 + pf * 16 + kg * 4 + j;
                sloc[((size_t)chunk * HDIM_ + p) * STATE_ + n] = (f16)acc[pf][nf][j];
            }
        }
}

// ---------------- SSD phase B: sequential inter-chunk state recurrence (f16 store) ----------------
__global__ __launch_bounds__(256) void chunk_scan_k(f16* __restrict__ sloc,
                                                    const float* __restrict__ cdecay) {
    int bh = blockIdx.x >> 6;
    int el = (blockIdx.x & 63) * 256 + threadIdx.x;  // 0..16383 within (p,n)
    float s = 0.f;
    for (int c = 0; c < NC_; ++c) {
        size_t chunk = (size_t)bh * NC_ + c;
        f16* ptr = sloc + chunk * (size_t)(STATE_*HDIM_) + el;
        float tmp = (float)*ptr;
        *ptr = (f16)s;               // becomes S_in for this chunk
        s = cdecay[chunk] * s + tmp;
    }
}

// ---------------- SSD phase 3 (MFMA): Y = [P | eA*C] . [X^T | S_in^T]^T + d*x ; GN stats ----------------
__global__ __launch_bounds__(256) void ssd_phase3(const f16* __restrict__ bc,
                                                  const f16* __restrict__ pbuf,
                                                  const f16* __restrict__ xT,
                                                  const f16* __restrict__ sloc,
                                                  const f16* __restrict__ xch,
                                                  const float* __restrict__ eAbuf,
                                                  const float* __restrict__ dparam,
                                                  f16* __restrict__ ybuf,
                                                  float* __restrict__ gstats) {
    __shared__ float red[512];
    const int tid = threadIdx.x;
    const int chunk = blockIdx.x;
    const int bh = chunk / NC_;
    const int ck = chunk - bh * NC_;
    const int b = bh >> 3, h = bh & 7;
    const int m0 = b * L_ + ck * Q_;
    const int w = tid >> 6, lane = tid & 63;
    const int r = lane & 15, kg = lane >> 4;

    float eA[4];
#pragma unroll
    for (int ft = 0; ft < 4; ++ft)
        eA[ft] = eAbuf[(size_t)(m0 + ft * 16 + r) * HEADS_ + h];

    f32x4 acc[4][4];
#pragma unroll
    for (int i = 0; i < 4; ++i)
#pragma unroll
        for (int j = 0; j < 4; ++j) acc[i][j] = (f32x4)0.f;

#pragma unroll
    for (int ks = 0; ks < 4; ++ks) {
        half8 a[4], bfr[4];
#pragma unroll
        for (int ft = 0; ft < 4; ++ft) {
            int t = ft * 16 + r;
            if (ks < 2) {
                a[ft] = *(const half8*)&pbuf[((size_t)chunk * Q_ + t) * Q_ + ks * 32 + kg * 8];
            } else {
                half8 c = *(const half8*)&bc[(size_t)(m0 + t) * BCS_ + 512 + h * STATE_ + (ks - 2) * 32 + kg * 8];
                half8 sc;
#pragma unroll
                for (int j = 0; j < 8; ++j) sc[j] = (f16)(eA[ft] * (float)c[j]);
                a[ft] = sc;
            }
        }
#pragma unroll
        for (int pf = 0; pf < 4; ++pf) {
            int p = w * 64 + pf * 16 + r;
            if (ks < 2)
                bfr[pf] = *(const half8*)&xT[((size_t)bh * HDIM_ + p) * L_ + ck * Q_ + ks * 32 + kg * 8];
            else
                bfr[pf] = *(const half8*)&sloc[((size_t)chunk * HDIM_ + p) * STATE_ + (ks - 2) * 32 + kg * 8];
        }
#pragma unroll
        for (int ft = 0; ft < 4; ++ft)
#pragma unroll
            for (int pf = 0; pf < 4; ++pf)
                acc[ft][pf] = __builtin_amdgcn_mfma_f32_16x16x32_f16(a[ft], bfr[pf], acc[ft][pf], 0, 0, 0);
    }

    const float d = dparam[h];
    float lsum = 0.f, lsq = 0.f;
#pragma unroll
    for (int ft = 0; ft < 4; ++ft)
#pragma unroll
        for (int pf = 0; pf < 4; ++pf) {
            int p = w * 64 + pf * 16 + r;
#pragma unroll
            for (int j = 0; j < 4; ++j) {
                int t = ft * 16 + kg * 4 + j;
                size_t off = (size_t)(m0 + t) * INNER_ + h * HDIM_ + p;
                float y = acc[ft][pf][j] + d * (float)xch[off];
                ybuf[off] = (f16)y;
                lsum += y; lsq += y * y;
            }
        }
    __syncthreads();
    red[tid] = lsum; red[256 + tid] = lsq;
    __syncthreads();
    for (int st = 128; st > 0; st >>= 1) {
        if (tid < st) { red[tid] += red[tid + st]; red[256 + tid] += red[256 + tid + st]; }
        __syncthreads();
    }
    if (tid == 0) {
        atomicAdd(&gstats[bh * 2 + 0], red[0]);
        atomicAdd(&gstats[bh * 2 + 1], red[256]);
    }
}

// ---------------- GroupNorm finalize + gate: g = (norm(y)*w+b) * silu(z) ----------------
__global__ __launch_bounds__(256) void gn_gate_h(const f16* __restrict__ ybuf,
                                                 const f16* __restrict__ xz,
                                                 const float* __restrict__ gstats,
                                                 const float* __restrict__ gnw,
                                                 const float* __restrict__ gnb,
                                                 f16* __restrict__ g) {
    int idx = blockIdx.x * 256 + threadIdx.x;    // over M_*INNER_/8
    int c8 = (idx & (INNER_/8 - 1)) * 8;
    int m = idx >> 8;
    int bh = (m >> 11) * HEADS_ + (c8 >> 8);
    const float cnt = (float)(L_ * HDIM_);
    float mean = gstats[bh*2] / cnt;
    float var  = gstats[bh*2+1] / cnt - mean*mean;
    float rstd = rsqrtf(var + EPS_);
    size_t off = (size_t)m * INNER_ + c8;
    half8 yv = *(const half8*)&ybuf[off];
    half8 zv = *(const half8*)&xz[(size_t)m * XZS_ + INNER_ + c8];
    float4 w0 = *(const float4*)&gnw[c8], w1 = *(const float4*)&gnw[c8+4];
    float4 b0 = *(const float4*)&gnb[c8], b1 = *(const float4*)&gnb[c8+4];
    float wv[8] = {w0.x, w0.y, w0.z, w0.w, w1.x, w1.y, w1.z, w1.w};
    float bv[8] = {b0.x, b0.y, b0.z, b0.w, b1.x, b1.y, b1.z, b1.w};
    half8 o;
#pragma unroll
    for (int j = 0; j < 8; ++j) {
        float v = ((float)yv[j] - mean) * rstd * wv[j] + bv[j];
        o[j] = (f16)(v * siluf((float)zv[j]));
    }
    *(half8*)&g[off] = o;
}

// ---------------- launch ----------------
extern "C" void kernel_launch(void* const* d_in, const int* in_sizes, int n_in,
                              void* d_out, int out_size, void* d_ws, size_t ws_size,
                              hipStream_t stream) {
    const float* input  = (const float*)d_in[0];
    const float* Wx     = (const float*)d_in[1];
    const float* Wz     = (const float*)d_in[2];
    const float* conv_w = (const float*)d_in[3];
    const float* conv_b = (const float*)d_in[4];
    const float* Wb     = (const float*)d_in[5];
    const float* Wc     = (const float*)d_in[6];
    const float* Wdt    = (const float*)d_in[7];
    const float* b_dt   = (const float*)d_in[8];
    const float* log_a  = (const float*)d_in[9];
    const float* d_par  = (const float*)d_in[10];
    const float* gn_w   = (const float*)d_in[11];
    const float* gn_b   = (const float*)d_in[12];
    const float* Wout   = (const float*)d_in[13];
    float* out = (float*)d_out;

    float* ws = (float*)d_ws;
    size_t off = 0;
    auto alloc = [&](size_t nfloats) { float* p = ws + off; off += (nfloats + 63) & ~(size_t)63; return p; };
    f16* input_h = (f16*)alloc((size_t)M_*DIM_/2);
    f16* wxz_h   = (f16*)alloc((size_t)XZS_*DIM_/2);
    f16* wbc_h   = (f16*)alloc((size_t)BCS_*INNER_/2);
    f16* wout_h  = (f16*)alloc((size_t)DIM_*INNER_/2);
    f16* xz_h    = (f16*)alloc((size_t)M_*XZS_/2);
    f16* xconv_h = (f16*)alloc((size_t)M_*INNER_/2);
    f16* xT_h    = (f16*)alloc((size_t)M_*INNER_/2);
    f16* gbuf_h  = (f16*)alloc((size_t)M_*INNER_/2);
    f16* bcmat_h = (f16*)alloc((size_t)M_*BCS_/2);
    f16* pbuf_h  = (f16*)alloc((size_t)NCHUNK_*Q_*Q_/2);
    f16* bwT_h   = (f16*)alloc((size_t)NCHUNK_*Q_*Q_/2);
    f16* sloc_h  = (f16*)alloc((size_t)NCHUNK_*STATE_*HDIM_/2);
    f16* ybuf_h  = (f16*)alloc((size_t)M_*INNER_/2);
    float* dtb   = alloc((size_t)M_*HEADS_);
    float* eAb   = alloc((size_t)M_*HEADS_);
    float* wbuf  = alloc((size_t)NCHUNK_*Q_);
    float* cdec  = alloc((size_t)NCHUNK_);
    float* gstat = alloc((size_t)2*B_*HEADS_);

    dim3 blk(256);

    cast_all<<<12288, blk, 0, stream>>>(input, Wx, Wz, Wb, Wc, Wout,
                                        input_h, wxz_h, wbc_h, wout_h);
    hgemm<128,true><<<dim3(XZS_/128, M_/128), blk, 0, stream>>>(input_h, wxz_h, xz_h, DIM_, XZS_);
    conv_silu_dt<<<M_, blk, 0, stream>>>(xz_h, conv_w, conv_b, Wdt, b_dt, xconv_h, dtb);
    hgemm<64,true><<<dim3(BCS_/64, M_/128), blk, 0, stream>>>(xconv_h, wbc_h, bcmat_h, INNER_, BCS_);
    xpose_k<<<2048, blk, 0, stream>>>(xconv_h, xT_h);
    ssd_phase1<<<NCHUNK_, blk, 0, stream>>>(bcmat_h, dtb, log_a, pbuf_h, eAb, wbuf, cdec);
    bwt_k<<<NCHUNK_, blk, 0, stream>>>(bcmat_h, wbuf, bwT_h);
    ssd_phase2<<<NCHUNK_, blk, 0, stream>>>(xT_h, bwT_h, sloc_h);
    chunk_scan_k<<<B_*HEADS_*64, blk, 0, stream>>>(sloc_h, cdec);
    hipMemsetAsync(gstat, 0, 2*B_*HEADS_*sizeof(float), stream);
    ssd_phase3<<<NCHUNK_, blk, 0, stream>>>(bcmat_h, pbuf_h, xT_h, sloc_h, xconv_h,
                                            eAb, d_par, ybuf_h, gstat);
    gn_gate_h<<<(M_*(INNER_/8))/256, blk, 0, stream>>>(ybuf_h, xz_h, gstat, gn_w, gn_b, gbuf_h);
    hgemm<64,false><<<dim3(DIM_/64, M_/128), blk, 0, stream>>>(gbuf_h, wout_h, out, INNER_, DIM_);
}